// Round 1
// baseline (2647.532 us; speedup 1.0000x reference)
//
#include <hip/hip_runtime.h>

// Tacotron2 decoder (teacher-forced, eval) — fp32 baseline.
// B=16 T=1024 H=512 M=80, 8 heads x 64.
constexpr int B_ = 16, T_ = 1024, H_ = 512, M_ = 80;
constexpr int NH_ = 8, D_ = 64;
constexpr int N_ = B_ * T_;  // 16384 rows

// ---------------------------------------------------------------------------
// Generic tiled GEMM: C = act(A @ W^T + bias)
// A: (N_, K) row-major (with AMODE variants), W: (Hout, K) row-major.
// Tile 64x64, BK template, 256 threads, 4x4 micro-tile per thread.
// AMODE: 0 = plain A; 1 = time-shifted target_mel (prev frame, zeros at t=0)
// EMODE: 0 = plain store (row stride Hout); 1 = relu store; 2 = per-head QKV
//        layout out[((b*8+head)*1024 + t)*64 + d]
// CBOUND: bounds-check cols against Hout (for Hout=80 mel projection)
// ---------------------------------------------------------------------------
template <int BK, int AMODE, int EMODE, bool CBOUND>
__global__ __launch_bounds__(256) void gemm_kernel(
    const float* __restrict__ A, const float* __restrict__ W,
    const float* __restrict__ bias, float* __restrict__ Cout, int K, int Hout) {
  __shared__ __align__(16) float As[BK][68];
  __shared__ __align__(16) float Ws[BK][68];

  const int tid = threadIdx.x;
  const int tx = tid & 15, ty = tid >> 4;
  const int r0 = blockIdx.x * 64, c0 = blockIdx.y * 64;

  float acc[4][4] = {};

  constexpr int NF4 = 64 * BK / 4;  // float4 loads per tile

  for (int k0 = 0; k0 < K; k0 += BK) {
    __syncthreads();
    // stage A tile (transposed to As[kk][row]) — coalesced float4 along K
    for (int f = tid; f < NF4; f += 256) {
      const int lin = f * 4;
      const int r = lin / BK, kk = lin % BK;
      const int rg = r0 + r;
      float4 val;
      if (AMODE == 0) {
        val = *(const float4*)(A + (size_t)rg * K + k0 + kk);
      } else {  // shifted mel: prev[t] = (t==0) ? 0 : tmel[t-1]
        const int t = rg & (T_ - 1);
        if (t == 0)
          val = make_float4(0.f, 0.f, 0.f, 0.f);
        else
          val = *(const float4*)(A + (size_t)(rg - 1) * M_ + k0 + kk);
      }
      As[kk + 0][r] = val.x; As[kk + 1][r] = val.y;
      As[kk + 2][r] = val.z; As[kk + 3][r] = val.w;
    }
    // stage W tile
    for (int f = tid; f < NF4; f += 256) {
      const int lin = f * 4;
      const int c = lin / BK, kk = lin % BK;
      const int cg = c0 + c;
      float4 val = make_float4(0.f, 0.f, 0.f, 0.f);
      if (!CBOUND || cg < Hout)
        val = *(const float4*)(W + (size_t)cg * K + k0 + kk);
      Ws[kk + 0][c] = val.x; Ws[kk + 1][c] = val.y;
      Ws[kk + 2][c] = val.z; Ws[kk + 3][c] = val.w;
    }
    __syncthreads();
#pragma unroll
    for (int kk = 0; kk < BK; ++kk) {
      const float4 a4 = *(const float4*)&As[kk][ty * 4];
      const float4 w4 = *(const float4*)&Ws[kk][tx * 4];
      const float av[4] = {a4.x, a4.y, a4.z, a4.w};
      const float wv[4] = {w4.x, w4.y, w4.z, w4.w};
#pragma unroll
      for (int i = 0; i < 4; ++i)
#pragma unroll
        for (int j = 0; j < 4; ++j) acc[i][j] += av[i] * wv[j];
    }
  }

#pragma unroll
  for (int i = 0; i < 4; ++i) {
    const int r = r0 + ty * 4 + i;
#pragma unroll
    for (int j = 0; j < 4; ++j) {
      const int c = c0 + tx * 4 + j;
      if (CBOUND && c >= Hout) continue;
      float v = acc[i][j] + bias[c];
      if (EMODE == 1) v = fmaxf(v, 0.f);
      if (EMODE == 2) {
        const int b = r >> 10, t = r & (T_ - 1);
        const int head = c >> 6, d = c & 63;
        Cout[(((size_t)(b * NH_ + head) * T_ + t) << 6) + d] = v;
      } else {
        Cout[(size_t)r * Hout + c] = v;
      }
    }
  }
}

// ---------------------------------------------------------------------------
// Flash-style attention, fp32. One block per (b, head, q-tile of 64).
// q/k/v in (B, NH, T, D) layout; q pre-scaled by 1/8 at staging.
// ctx written as (B, T, H) = (b, t, head*64+d).
// ---------------------------------------------------------------------------
__global__ __launch_bounds__(256) void attn_kernel(
    const float* __restrict__ q, const float* __restrict__ k,
    const float* __restrict__ v, float* __restrict__ ctx) {
  const int qt = blockIdx.x, head = blockIdx.y, b = blockIdx.z;
  const float* qbh = q + ((size_t)(b * NH_ + head) * T_) * D_;
  const float* kbh = k + ((size_t)(b * NH_ + head) * T_) * D_;
  const float* vbh = v + ((size_t)(b * NH_ + head) * T_) * D_;

  __shared__ float qs[64][65];
  __shared__ float ks[64][65];
  __shared__ float vs[64][65];
  __shared__ float ss[64][65];
  __shared__ float mrow[64], lrow[64], crow[64];

  const int tid = threadIdx.x;
  const int tx = tid & 15, ty = tid >> 4;

  // stage q tile, scaled by 1/sqrt(64)
  for (int f = tid; f < 64 * 16; f += 256) {
    const int r = f >> 4, dq = (f & 15) * 4;
    const float4 val = *(const float4*)(qbh + (size_t)(qt * 64 + r) * D_ + dq);
    qs[r][dq + 0] = val.x * 0.125f; qs[r][dq + 1] = val.y * 0.125f;
    qs[r][dq + 2] = val.z * 0.125f; qs[r][dq + 3] = val.w * 0.125f;
  }
  if (tid < 64) { mrow[tid] = -1e30f; lrow[tid] = 0.f; }
  float o[4][4] = {};
  __syncthreads();

  for (int kt = 0; kt < T_ / 64; ++kt) {
    for (int f = tid; f < 64 * 16; f += 256) {
      const int r = f >> 4, dq = (f & 15) * 4;
      const float4 kv = *(const float4*)(kbh + (size_t)(kt * 64 + r) * D_ + dq);
      const float4 vv = *(const float4*)(vbh + (size_t)(kt * 64 + r) * D_ + dq);
      ks[r][dq + 0] = kv.x; ks[r][dq + 1] = kv.y;
      ks[r][dq + 2] = kv.z; ks[r][dq + 3] = kv.w;
      vs[r][dq + 0] = vv.x; vs[r][dq + 1] = vv.y;
      vs[r][dq + 2] = vv.z; vs[r][dq + 3] = vv.w;
    }
    __syncthreads();
    // S = q @ k^T  (4x4 per thread)
    float s[4][4] = {};
    for (int d = 0; d < D_; ++d) {
      float av[4], wv[4];
#pragma unroll
      for (int i = 0; i < 4; ++i) av[i] = qs[ty * 4 + i][d];
#pragma unroll
      for (int j = 0; j < 4; ++j) wv[j] = ks[tx * 4 + j][d];
#pragma unroll
      for (int i = 0; i < 4; ++i)
#pragma unroll
        for (int j = 0; j < 4; ++j) s[i][j] += av[i] * wv[j];
    }
#pragma unroll
    for (int i = 0; i < 4; ++i)
#pragma unroll
      for (int j = 0; j < 4; ++j) ss[ty * 4 + i][tx * 4 + j] = s[i][j];
    __syncthreads();
    // online softmax row stats (rows owned by first 64 lanes)
    if (tid < 64) {
      const int r = tid;
      const float mold = mrow[r];
      float tmax = mold;
#pragma unroll 8
      for (int j = 0; j < 64; ++j) tmax = fmaxf(tmax, ss[r][j]);
      const float corr = __expf(mold - tmax);
      float sum = 0.f;
#pragma unroll 8
      for (int j = 0; j < 64; ++j) {
        const float p = __expf(ss[r][j] - tmax);
        ss[r][j] = p;
        sum += p;
      }
      mrow[r] = tmax;
      lrow[r] = lrow[r] * corr + sum;
      crow[r] = corr;
    }
    __syncthreads();
    // o = o*corr + P @ V
    float cr[4];
#pragma unroll
    for (int i = 0; i < 4; ++i) cr[i] = crow[ty * 4 + i];
#pragma unroll
    for (int i = 0; i < 4; ++i)
#pragma unroll
      for (int j = 0; j < 4; ++j) o[i][j] *= cr[i];
    for (int kr = 0; kr < 64; ++kr) {
      float pv[4], vv[4];
#pragma unroll
      for (int i = 0; i < 4; ++i) pv[i] = ss[ty * 4 + i][kr];
#pragma unroll
      for (int j = 0; j < 4; ++j) vv[j] = vs[kr][tx * 4 + j];
#pragma unroll
      for (int i = 0; i < 4; ++i)
#pragma unroll
        for (int j = 0; j < 4; ++j) o[i][j] += pv[i] * vv[j];
    }
    __syncthreads();
  }
#pragma unroll
  for (int i = 0; i < 4; ++i) {
    const int t = qt * 64 + ty * 4 + i;
    const float inv = 1.f / lrow[ty * 4 + i];
#pragma unroll
    for (int j = 0; j < 4; ++j)
      ctx[(size_t)(b * T_ + t) * H_ + head * 64 + tx * 4 + j] = o[i][j] * inv;
  }
}

// ---------------------------------------------------------------------------
// Fused single-step-from-zero LSTM: h = sig(o)*tanh(sig(i)*tanh(g)).
// Gates = x @ W_ih^T + (b_ih + b_hh); forget gate & W_hh are dead (h0=c0=0).
// KMODE: 0 -> K=512 single input; 1 -> K=1024 concat(A | A2), 512 each.
// ---------------------------------------------------------------------------
template <int KMODE>
__global__ __launch_bounds__(256) void lstm_kernel(
    const float* __restrict__ A, const float* __restrict__ A2,
    const float* __restrict__ Wih, const float* __restrict__ bih,
    const float* __restrict__ bhh, float* __restrict__ Hout_) {
  constexpr int K = KMODE ? 1024 : 512;
  constexpr int BK = 32;
  __shared__ __align__(16) float As[BK][68];
  __shared__ __align__(16) float Ws[3][BK][68];

  const int tid = threadIdx.x;
  const int tx = tid & 15, ty = tid >> 4;
  const int r0 = blockIdx.x * 64, c0 = blockIdx.y * 64;

  float acc[3][4][4] = {};
  constexpr int NF4 = 64 * BK / 4;  // 512

  for (int k0 = 0; k0 < K; k0 += BK) {
    __syncthreads();
    for (int f = tid; f < NF4; f += 256) {
      const int lin = f * 4;
      const int r = lin / BK, kk = lin % BK;
      const int rg = r0 + r;
      float4 val;
      if (KMODE == 0) {
        val = *(const float4*)(A + (size_t)rg * 512 + k0 + kk);
      } else {
        const int kg = k0 + kk;  // tile never straddles the 512 boundary
        if (kg < 512)
          val = *(const float4*)(A + (size_t)rg * 512 + kg);
        else
          val = *(const float4*)(A2 + (size_t)rg * 512 + (kg - 512));
      }
      As[kk + 0][r] = val.x; As[kk + 1][r] = val.y;
      As[kk + 2][r] = val.z; As[kk + 3][r] = val.w;
    }
    for (int f = tid; f < 3 * NF4; f += 256) {
      const int lin = f * 4;
      const int g = lin / (64 * BK);
      const int rem = lin % (64 * BK);
      const int c = rem / BK, kk = rem % BK;
      const int go = (g == 0) ? 0 : 512 * (g + 1);  // gate rows: i=0, g=1024, o=1536
      const float4 val =
          *(const float4*)(Wih + (size_t)(go + c0 + c) * K + k0 + kk);
      Ws[g][kk + 0][c] = val.x; Ws[g][kk + 1][c] = val.y;
      Ws[g][kk + 2][c] = val.z; Ws[g][kk + 3][c] = val.w;
    }
    __syncthreads();
#pragma unroll
    for (int kk = 0; kk < BK; ++kk) {
      const float4 a4 = *(const float4*)&As[kk][ty * 4];
      const float av[4] = {a4.x, a4.y, a4.z, a4.w};
#pragma unroll
      for (int g = 0; g < 3; ++g) {
        const float4 w4 = *(const float4*)&Ws[g][kk][tx * 4];
        const float wv[4] = {w4.x, w4.y, w4.z, w4.w};
#pragma unroll
        for (int i = 0; i < 4; ++i)
#pragma unroll
          for (int j = 0; j < 4; ++j) acc[g][i][j] += av[i] * wv[j];
      }
    }
  }

#pragma unroll
  for (int j = 0; j < 4; ++j) {
    const int c = c0 + tx * 4 + j;
    const float bi = bih[c] + bhh[c];
    const float bg = bih[1024 + c] + bhh[1024 + c];
    const float bo = bih[1536 + c] + bhh[1536 + c];
#pragma unroll
    for (int i = 0; i < 4; ++i) {
      const int r = r0 + ty * 4 + i;
      const float gi = acc[0][i][j] + bi;
      const float gg = acc[1][i][j] + bg;
      const float go = acc[2][i][j] + bo;
      const float sig_i = 1.f / (1.f + __expf(-gi));
      const float sig_o = 1.f / (1.f + __expf(-go));
      const float tg = 1.f - 2.f / (__expf(2.f * gg) + 1.f);
      const float cc = sig_i * tg;
      const float tc = 1.f - 2.f / (__expf(2.f * cc) + 1.f);
      Hout_[(size_t)r * 512 + c] = sig_o * tc;
    }
  }
}

// ---------------------------------------------------------------------------
extern "C" void kernel_launch(void* const* d_in, const int* in_sizes, int n_in,
                              void* d_out, int out_size, void* d_ws,
                              size_t ws_size, hipStream_t stream) {
  const float* enc = (const float*)d_in[0];
  const float* tmel = (const float*)d_in[1];
  const float* w_pre = (const float*)d_in[2];
  const float* b_pre = (const float*)d_in[3];
  const float* inw = (const float*)d_in[4];
  const float* inb = (const float*)d_in[5];
  const float* outw = (const float*)d_in[6];
  const float* outb = (const float*)d_in[7];
  const float* wih0 = (const float*)d_in[8];
  const float* bih0 = (const float*)d_in[10];
  const float* bhh0 = (const float*)d_in[11];
  const float* wih1 = (const float*)d_in[12];
  const float* bih1 = (const float*)d_in[14];
  const float* bhh1 = (const float*)d_in[15];
  const float* wmel = (const float*)d_in[16];
  const float* bmel = (const float*)d_in[17];

  float* ws = (float*)d_ws;
  const size_t SEG = (size_t)N_ * H_;  // 8388608 floats per region
  float* pre = ws;
  float* qb = ws + SEG;
  float* kb = ws + 2 * SEG;
  float* vb = ws + 3 * SEG;
  float* ctx = ws + 4 * SEG;
  float* aout = vb;  // v dead after attention
  float* h1 = qb;    // q dead after attention
  float* h2 = kb;    // k dead after attention
  float* out = (float*)d_out;

  const dim3 blk(256);
  // prenet: pre = relu(prev @ w_pre^T + b_pre), K=80
  gemm_kernel<16, 1, 1, false>
      <<<dim3(N_ / 64, H_ / 64), blk, 0, stream>>>(tmel, w_pre, b_pre, pre, 80, H_);
  // QKV projections into (B, NH, T, D)
  gemm_kernel<32, 0, 2, false>
      <<<dim3(N_ / 64, H_ / 64), blk, 0, stream>>>(pre, inw, inb, qb, H_, H_);
  gemm_kernel<32, 0, 2, false><<<dim3(N_ / 64, H_ / 64), blk, 0, stream>>>(
      enc, inw + 512 * 512, inb + 512, kb, H_, H_);
  gemm_kernel<32, 0, 2, false><<<dim3(N_ / 64, H_ / 64), blk, 0, stream>>>(
      enc, inw + 1024 * 512, inb + 1024, vb, H_, H_);
  // fused attention -> ctx (B,T,H)
  attn_kernel<<<dim3(T_ / 64, NH_, B_), blk, 0, stream>>>(qb, kb, vb, ctx);
  // out projection
  gemm_kernel<32, 0, 0, false>
      <<<dim3(N_ / 64, H_ / 64), blk, 0, stream>>>(ctx, outw, outb, aout, H_, H_);
  // LSTM layers (fused gates + activations)
  lstm_kernel<1><<<dim3(N_ / 64, H_ / 64), blk, 0, stream>>>(pre, aout, wih0,
                                                             bih0, bhh0, h1);
  lstm_kernel<0><<<dim3(N_ / 64, H_ / 64), blk, 0, stream>>>(h1, nullptr, wih1,
                                                             bih1, bhh1, h2);
  // mel projection (Hout=80, bounds-checked)
  gemm_kernel<32, 0, 0, true>
      <<<dim3(N_ / 64, 2), blk, 0, stream>>>(h2, wmel, bmel, out, H_, 80);
}

// Round 2
// 512.727 us; speedup vs baseline: 5.1636x; 5.1636x over previous
//
#include <hip/hip_runtime.h>

// Tacotron2 decoder — round 2: fp16 MFMA everywhere (fp32 accumulate).
// R1: fp32 vector baseline 2647us (attn 1034us, MfmaUtil=0, VALU-bound).
// R2: m97-style 128x128 GEMM (global_load_lds + XOR-swizzle + 16x16x32 MFMA),
//     waveless-sync flash attention with direct-global K/V and LDS P-transpose.

typedef _Float16 f16;
typedef _Float16 f16x8 __attribute__((ext_vector_type(8)));
typedef _Float16 f16x4 __attribute__((ext_vector_type(4)));
typedef float f32x4 __attribute__((ext_vector_type(4)));

constexpr int B_ = 16, T_ = 1024, H_ = 512, M_ = 80;
constexpr int NH_ = 8, D_ = 64;
constexpr int N_ = B_ * T_;  // 16384 rows

#define MFMA16(a, b, c) __builtin_amdgcn_mfma_f32_16x16x32_f16(a, b, c, 0, 0, 0)

__device__ __forceinline__ void gload_lds16(const f16* g, f16* l) {
  __builtin_amdgcn_global_load_lds(
      (const __attribute__((address_space(1))) void*)g,
      (__attribute__((address_space(3))) void*)l, 16, 0, 0);
}

// ---------------------------------------------------------------------------
// MFMA GEMM: C = epi((A @ Wt^T + bias [+ bias2]) * scale)
// A: (M_, K) f16 row-major (CONCATA: cols 0-511 from A, 512-1023 from A2,
// both stride 512). Wt: (N, K) f16 row-major. 128x128 tile, BK=64, 4 waves.
// LDS linear rows of 128B; XOR swizzle (chunk ^= row&7) applied on the
// GLOBAL source (global_load_lds dest must be linear) and on ds_read.
// EPI: 0 plain f16, 1 relu f16, 3 per-head transposed V layout (B,NH,D,T),
//      4 fp32 store (mel). NCHK: clamp/guard cols vs N (N=80).
// ---------------------------------------------------------------------------
template <int EPI, bool CONCATA, bool NCHK>
__global__ __launch_bounds__(256) void mgemm(
    const f16* __restrict__ A, const f16* __restrict__ A2,
    const f16* __restrict__ Wt, const float* __restrict__ bias,
    const float* __restrict__ bias2, float scale, void* __restrict__ outp,
    int K, int N) {
  __shared__ f16 As[128 * 64];
  __shared__ f16 Bs[128 * 64];
  const int tid = threadIdx.x;
  const int lane = tid & 63, wid = tid >> 6;
  const int lq = lane & 15, lg = lane >> 4;
  const int wm = wid >> 1, wn = wid & 1;
  const int r0 = blockIdx.x * 128, c0 = blockIdx.y * 128;

  f32x4 acc[4][4] = {};

  for (int k0 = 0; k0 < K; k0 += 64) {
    // stage A tile (16KB) + B tile (16KB); linear LDS dest, swizzled source
#pragma unroll
    for (int it = 0; it < 4; ++it) {
      const int off = it * 4096 + wid * 1024 + lane * 16;  // LDS byte offset
      const int row = off >> 7;
      const int cb = (off >> 4) & 7;
      const int kc = k0 + ((cb ^ (row & 7)) << 3);
      const f16* src;
      if (CONCATA) {
        src = (kc < 512) ? (A + (size_t)(r0 + row) * 512 + kc)
                         : (A2 + (size_t)(r0 + row) * 512 + (kc - 512));
      } else {
        src = A + (size_t)(r0 + row) * K + kc;
      }
      gload_lds16(src, (f16*)((char*)As + off));
    }
#pragma unroll
    for (int it = 0; it < 4; ++it) {
      const int off = it * 4096 + wid * 1024 + lane * 16;
      const int row = off >> 7;
      const int cb = (off >> 4) & 7;
      int crow = c0 + row;
      if (NCHK) crow = crow < N ? crow : N - 1;
      gload_lds16(Wt + (size_t)crow * K + k0 + ((cb ^ (row & 7)) << 3),
                  (f16*)((char*)Bs + off));
    }
    __syncthreads();  // compiler drains vmcnt before s_barrier
#pragma unroll
    for (int kk = 0; kk < 2; ++kk) {
      f16x8 af[4], bf[4];
#pragma unroll
      for (int m = 0; m < 4; ++m) {
        const int row = wm * 64 + m * 16 + lq;
        af[m] = *(const f16x8*)((const char*)As + row * 128 +
                                (((kk * 4 + lg) ^ (row & 7)) << 4));
      }
#pragma unroll
      for (int n = 0; n < 4; ++n) {
        const int row = wn * 64 + n * 16 + lq;
        bf[n] = *(const f16x8*)((const char*)Bs + row * 128 +
                                (((kk * 4 + lg) ^ (row & 7)) << 4));
      }
#pragma unroll
      for (int m = 0; m < 4; ++m)
#pragma unroll
        for (int n = 0; n < 4; ++n) acc[m][n] = MFMA16(af[m], bf[n], acc[m][n]);
    }
    __syncthreads();  // protect LDS before next-iter staging
  }

  // epilogue — C/D layout: col = lane&15, row = (lane>>4)*4 + reg
#pragma unroll
  for (int m = 0; m < 4; ++m) {
    const int rbase = r0 + wm * 64 + m * 16 + lg * 4;
#pragma unroll
    for (int n = 0; n < 4; ++n) {
      const int col = c0 + wn * 64 + n * 16 + lq;
      if (NCHK && col >= N) continue;
      const float bsum = bias[col] + (bias2 ? bias2[col] : 0.f);
      const f32x4 a = acc[m][n];
      if (EPI == 3) {  // V: (B,NH,D,T), 4 consecutive t per lane -> 8B store
        const int b = rbase >> 10, t = rbase & (T_ - 1);
        const int head = col >> 6, d = col & 63;
        f16x4 pk;
#pragma unroll
        for (int r = 0; r < 4; ++r) pk[r] = (f16)((a[r] + bsum) * scale);
        *(f16x4*)((f16*)outp + ((size_t)((b * NH_ + head) * D_ + d)) * T_ + t) =
            pk;
      } else {
#pragma unroll
        for (int r = 0; r < 4; ++r) {
          const int row = rbase + r;
          float v = (a[r] + bsum) * scale;
          if (EPI == 1) v = fmaxf(v, 0.f);
          if (EPI == 4)
            ((float*)outp)[(size_t)row * N + col] = v;
          else
            ((f16*)outp)[(size_t)row * N + col] = (f16)v;
        }
      }
    }
  }
}

// ---------------------------------------------------------------------------
// Flash attention, fp16 MFMA. Grid (16 qtiles, 8 heads, 16 batch), 4
// independent waves (16 q-rows each), zero __syncthreads. K/V read directly
// from global (L2/L3-resident). q,k: (B,T,H) pre-scaled q; v: (B,NH,D,T).
// P transposed to MFMA-A layout through a per-wave 2KB swizzled LDS buffer.
// ---------------------------------------------------------------------------
__global__ __launch_bounds__(256) void attn_mfma(
    const f16* __restrict__ q, const f16* __restrict__ k,
    const f16* __restrict__ vT, f16* __restrict__ ctx) {
  __shared__ f16 plds[4][1024];
  const int qt = blockIdx.x, head = blockIdx.y, b = blockIdx.z;
  const int tid = threadIdx.x, lane = tid & 63, wid = tid >> 6;
  const int lq = lane & 15, lg = lane >> 4;
  const int bh = b * NH_ + head;
  const int qbase = qt * 64 + wid * 16;

  const f16* qp = q + ((size_t)(b * T_) + qbase) * H_ + head * D_;
  f16x8 aq[2];
#pragma unroll
  for (int kk = 0; kk < 2; ++kk)
    aq[kk] = *(const f16x8*)(qp + lq * H_ + kk * 32 + lg * 8);

  float m_run[4], l_run[4];
#pragma unroll
  for (int r = 0; r < 4; ++r) {
    m_run[r] = -1e30f;
    l_run[r] = 0.f;
  }
  f32x4 acc_o[4] = {};

  const f16* kbase = k + ((size_t)(b * T_)) * H_ + head * D_;
  const f16* vbase = vT + (size_t)bh * D_ * T_;
  char* pw = (char*)&plds[wid][0];

  for (int kt = 0; kt < T_ / 64; ++kt) {
    // S strip (16 x 64) = Q(16x64) @ K^T
    const f16* kp = kbase + (size_t)(kt * 64) * H_;
    f32x4 s[4] = {};
#pragma unroll
    for (int n = 0; n < 4; ++n)
#pragma unroll
      for (int kk = 0; kk < 2; ++kk) {
        const f16x8 bk =
            *(const f16x8*)(kp + (size_t)(n * 16 + lq) * H_ + kk * 32 + lg * 8);
        s[n] = MFMA16(aq[kk], bk, s[n]);
      }
    // online softmax: rows lg*4+r live in 16-lane groups -> shfl_xor reduce
    float mx[4];
#pragma unroll
    for (int r = 0; r < 4; ++r)
      mx[r] = fmaxf(fmaxf(s[0][r], s[1][r]), fmaxf(s[2][r], s[3][r]));
#pragma unroll
    for (int off = 1; off <= 8; off <<= 1)
#pragma unroll
      for (int r = 0; r < 4; ++r)
        mx[r] = fmaxf(mx[r], __shfl_xor(mx[r], off, 64));
    float corr[4], sm[4], p[4][4];
#pragma unroll
    for (int r = 0; r < 4; ++r) {
      const float nm = fmaxf(m_run[r], mx[r]);
      corr[r] = __expf(m_run[r] - nm);
      m_run[r] = nm;
      sm[r] = 0.f;
    }
#pragma unroll
    for (int n = 0; n < 4; ++n)
#pragma unroll
      for (int r = 0; r < 4; ++r) {
        p[n][r] = __expf(s[n][r] - m_run[r]);
        sm[r] += p[n][r];
      }
#pragma unroll
    for (int off = 1; off <= 8; off <<= 1)
#pragma unroll
      for (int r = 0; r < 4; ++r) sm[r] += __shfl_xor(sm[r], off, 64);
#pragma unroll
    for (int r = 0; r < 4; ++r) l_run[r] = l_run[r] * corr[r] + sm[r];
#pragma unroll
    for (int n = 0; n < 4; ++n)
#pragma unroll
      for (int r = 0; r < 4; ++r) acc_o[n][r] *= corr[r];
    // P (C-layout) -> LDS (swizzled [row][col]) -> A-fragment reads
#pragma unroll
    for (int n = 0; n < 4; ++n)
#pragma unroll
      for (int r = 0; r < 4; ++r) {
        const int row = lg * 4 + r;
        *(f16*)(pw + row * 128 + ((n * 32 + lq * 2) ^ ((row & 7) << 4))) =
            (f16)p[n][r];
      }
    f16x8 pa[2];
#pragma unroll
    for (int kk = 0; kk < 2; ++kk)
      pa[kk] =
          *(const f16x8*)(pw + lq * 128 + (((kk * 4 + lg) ^ (lq & 7)) << 4));
    // O strip += P @ V  (V^T layout makes B-fragments contiguous in t)
    const f16* vp = vbase + kt * 64;
#pragma unroll
    for (int n = 0; n < 4; ++n)
#pragma unroll
      for (int kk = 0; kk < 2; ++kk) {
        const f16x8 bv =
            *(const f16x8*)(vp + (size_t)(n * 16 + lq) * T_ + kk * 32 + lg * 8);
        acc_o[n] = MFMA16(pa[kk], bv, acc_o[n]);
      }
  }
#pragma unroll
  for (int r = 0; r < 4; ++r) {
    const int t = qbase + lg * 4 + r;
    const float inv = 1.f / l_run[r];
#pragma unroll
    for (int n = 0; n < 4; ++n)
      ctx[((size_t)(b * T_) + t) * H_ + head * D_ + n * 16 + lq] =
          (f16)(acc_o[n][r] * inv);
  }
}

// ---------------------------------------------------------------------------
// Conversions + small fused ops
// ---------------------------------------------------------------------------
__global__ void conv_f32_f16(const float* __restrict__ in, f16* __restrict__ out,
                             int n4) {
  const int i = blockIdx.x * blockDim.x + threadIdx.x;
  if (i >= n4) return;
  const float4 v = ((const float4*)in)[i];
  f16x4 o = {(f16)v.x, (f16)v.y, (f16)v.z, (f16)v.w};
  ((f16x4*)out)[i] = o;
}

// prev-mel: pm[r][c] (16384 x 128): t==0 -> 0; c>=80 -> 0; else tmel[r-1][c]
__global__ void build_pm(const float* __restrict__ tmel, f16* __restrict__ pm) {
  const int i = blockIdx.x * blockDim.x + threadIdx.x;  // [0, 16384*32)
  const int r = i >> 5, c4 = (i & 31) * 4;
  const int t = r & (T_ - 1);
  f16x4 o = {};
  if (t != 0 && c4 < M_) {
    const float4 v = *(const float4*)(tmel + (size_t)(r - 1) * M_ + c4);
    o = {(f16)v.x, (f16)v.y, (f16)v.z, (f16)v.w};
  }
  *(f16x4*)(pm + (size_t)r * 128 + c4) = o;
}

// w_prenet padded K 80 -> 128 with zeros
__global__ void build_wp(const float* __restrict__ w, f16* __restrict__ wp) {
  const int i = blockIdx.x * blockDim.x + threadIdx.x;  // [0, 512*32)
  const int r = i >> 5, c4 = (i & 31) * 4;
  f16x4 o = {};
  if (c4 < M_) {
    const float4 v = *(const float4*)(w + (size_t)r * M_ + c4);
    o = {(f16)v.x, (f16)v.y, (f16)v.z, (f16)v.w};
  }
  *(f16x4*)(wp + (size_t)r * 128 + c4) = o;
}

// h = sigmoid(o) * tanh(sigmoid(i) * tanh(g))   (zero-state LSTM step)
__global__ void lstm_combine(const f16* __restrict__ gi, const f16* __restrict__ gg,
                             const f16* __restrict__ go, f16* __restrict__ h,
                             int n8) {
  const int i = blockIdx.x * blockDim.x + threadIdx.x;
  if (i >= n8) return;
  const f16x8 vi = ((const f16x8*)gi)[i];
  const f16x8 vg = ((const f16x8*)gg)[i];
  const f16x8 vo = ((const f16x8*)go)[i];
  f16x8 r;
#pragma unroll
  for (int j = 0; j < 8; ++j) {
    const float xi = (float)vi[j], xg = (float)vg[j], xo = (float)vo[j];
    const float si = 1.f / (1.f + __expf(-xi));
    const float so = 1.f / (1.f + __expf(-xo));
    const float tg = 2.f / (1.f + __expf(-2.f * xg)) - 1.f;
    const float c = si * tg;
    const float tc = 2.f / (1.f + __expf(-2.f * c)) - 1.f;
    r[j] = (f16)(so * tc);
  }
  ((f16x8*)h)[i] = r;
}

// ---------------------------------------------------------------------------
extern "C" void kernel_launch(void* const* d_in, const int* in_sizes, int n_in,
                              void* d_out, int out_size, void* d_ws,
                              size_t ws_size, hipStream_t stream) {
  const float* enc = (const float*)d_in[0];
  const float* tmel = (const float*)d_in[1];
  const float* w_pre = (const float*)d_in[2];
  const float* b_pre = (const float*)d_in[3];
  const float* inw = (const float*)d_in[4];
  const float* inb = (const float*)d_in[5];
  const float* outw = (const float*)d_in[6];
  const float* outb = (const float*)d_in[7];
  const float* wih0 = (const float*)d_in[8];
  const float* bih0 = (const float*)d_in[10];
  const float* bhh0 = (const float*)d_in[11];
  const float* wih1 = (const float*)d_in[12];
  const float* bih1 = (const float*)d_in[14];
  const float* bhh1 = (const float*)d_in[15];
  const float* wmel = (const float*)d_in[16];
  const float* bmel = (const float*)d_in[17];

  f16* wsh = (f16*)d_ws;
  const size_t SEG = (size_t)N_ * H_;  // 8388608 f16 per slot (16.8 MB)
  f16* EncB = wsh;                     // S0; reused as aout
  f16* h1 = wsh + SEG;                 // S1
  f16* pre = wsh + 2 * SEG;            // S2
  f16* qb = wsh + 3 * SEG;             // S3; reused as h2
  f16* kbuf = wsh + 4 * SEG;           // S4; reused as gate i
  f16* vTb = wsh + 5 * SEG;            // S5; reused as gate g
  f16* ctx = wsh + 6 * SEG;            // S6; reused as gate o
  f16* aout = EncB;
  f16* gi = kbuf;
  f16* gg = vTb;
  f16* go = ctx;
  f16* h2 = qb;
  // slot 7: converted weights + padded prev-mel (6.4M of 8.4M f16)
  f16* WP = wsh + 7 * SEG;                  // 512*128
  f16* WIN = WP + 512 * 128;                // 1536*512
  f16* WOUT = WIN + 1536 * 512;             // 512*512
  f16* WIH0 = WOUT + 512 * 512;             // 2048*1024
  f16* WIH1 = WIH0 + 2048 * 1024;           // 2048*512
  f16* WMEL = WIH1 + 2048 * 512;            // 80*512
  f16* PM = WMEL + 80 * 512;                // 16384*128

  const dim3 blk(256);
  auto cv = [&](const float* s, f16* d, int n) {
    conv_f32_f16<<<(n / 4 + 255) / 256, blk, 0, stream>>>(s, d, n / 4);
  };
  cv(enc, EncB, N_ * H_);
  cv(inw, WIN, 1536 * 512);
  cv(outw, WOUT, 512 * 512);
  cv(wih0, WIH0, 2048 * 1024);
  cv(wih1, WIH1, 2048 * 512);
  cv(wmel, WMEL, 80 * 512);
  build_pm<<<(N_ * 32) / 256, blk, 0, stream>>>(tmel, PM);
  build_wp<<<(512 * 32) / 256, blk, 0, stream>>>(w_pre, WP);

  const dim3 g512(N_ / 128, 4), g80(N_ / 128, 1);
  // prenet: pre = relu(PM @ WP^T + b_pre), K padded to 128
  mgemm<1, false, false><<<g512, blk, 0, stream>>>(PM, nullptr, WP, b_pre,
                                                   nullptr, 1.f, pre, 128, 512);
  // QKV (q pre-scaled by 1/sqrt(64)); v stored transposed (B,NH,D,T)
  mgemm<0, false, false><<<g512, blk, 0, stream>>>(pre, nullptr, WIN, inb,
                                                   nullptr, 0.125f, qb, 512, 512);
  mgemm<0, false, false><<<g512, blk, 0, stream>>>(
      EncB, nullptr, WIN + 512 * 512, inb + 512, nullptr, 1.f, kbuf, 512, 512);
  mgemm<3, false, false><<<g512, blk, 0, stream>>>(
      EncB, nullptr, WIN + 1024 * 512, inb + 1024, nullptr, 1.f, vTb, 512, 512);
  attn_mfma<<<dim3(T_ / 64, NH_, B_), blk, 0, stream>>>(qb, kbuf, vTb, ctx);
  // out projection
  mgemm<0, false, false><<<g512, blk, 0, stream>>>(ctx, nullptr, WOUT, outb,
                                                   nullptr, 1.f, aout, 512, 512);
  // LSTM0: gates i,g,o over concat(pre | aout), K=1024 (f, W_hh dead)
  mgemm<0, true, false><<<g512, blk, 0, stream>>>(
      pre, aout, WIH0, bih0, bhh0, 1.f, gi, 1024, 512);
  mgemm<0, true, false><<<g512, blk, 0, stream>>>(
      pre, aout, WIH0 + (size_t)1024 * 1024, bih0 + 1024, bhh0 + 1024, 1.f, gg,
      1024, 512);
  mgemm<0, true, false><<<g512, blk, 0, stream>>>(
      pre, aout, WIH0 + (size_t)1536 * 1024, bih0 + 1536, bhh0 + 1536, 1.f, go,
      1024, 512);
  lstm_combine<<<(int)(SEG / 8 + 255) / 256, blk, 0, stream>>>(gi, gg, go, h1,
                                                               (int)(SEG / 8));
  // LSTM1: K=512
  mgemm<0, false, false><<<g512, blk, 0, stream>>>(h1, nullptr, WIH1, bih1,
                                                   bhh1, 1.f, gi, 512, 512);
  mgemm<0, false, false><<<g512, blk, 0, stream>>>(
      h1, nullptr, WIH1 + (size_t)1024 * 512, bih1 + 1024, bhh1 + 1024, 1.f, gg,
      512, 512);
  mgemm<0, false, false><<<g512, blk, 0, stream>>>(
      h1, nullptr, WIH1 + (size_t)1536 * 512, bih1 + 1536, bhh1 + 1536, 1.f, go,
      512, 512);
  lstm_combine<<<(int)(SEG / 8 + 255) / 256, blk, 0, stream>>>(gi, gg, go, h2,
                                                               (int)(SEG / 8));
  // mel projection -> fp32 d_out (N=80, col-guarded)
  mgemm<4, false, true><<<g80, blk, 0, stream>>>(h2, nullptr, WMEL, bmel,
                                                 nullptr, 1.f, (float*)d_out,
                                                 512, 80);
}

// Round 3
// 364.176 us; speedup vs baseline: 7.2699x; 1.4079x over previous
//
#include <hip/hip_runtime.h>

// Tacotron2 decoder — round 3.
// R1: fp32 vector baseline 2647us (attn 1034us VALU-bound).
// R2: fp16 MFMA everywhere, 512us. attn 245us latency-bound (MfmaUtil 5.7%).
// R3: attn rewrite — swapped-operand QK^T and PV (lane-local softmax, packed
//     b64 P-transpose), LDS-staged double-buffered K/V via global_load_lds,
//     2 q-strips/wave for fragment reuse, stage-ahead pipeline, setprio.

typedef _Float16 f16;
typedef _Float16 f16x8 __attribute__((ext_vector_type(8)));
typedef _Float16 f16x4 __attribute__((ext_vector_type(4)));
typedef float f32x4 __attribute__((ext_vector_type(4)));

constexpr int B_ = 16, T_ = 1024, H_ = 512, M_ = 80;
constexpr int NH_ = 8, D_ = 64;
constexpr int N_ = B_ * T_;  // 16384 rows

#define MFMA16(a, b, c) __builtin_amdgcn_mfma_f32_16x16x32_f16(a, b, c, 0, 0, 0)

__device__ __forceinline__ void gload_lds16(const f16* g, f16* l) {
  __builtin_amdgcn_global_load_lds(
      (const __attribute__((address_space(1))) void*)g,
      (__attribute__((address_space(3))) void*)l, 16, 0, 0);
}

// ---------------------------------------------------------------------------
// MFMA GEMM: C = epi((A @ Wt^T + bias [+ bias2]) * scale)   [validated R2]
// 128x128 tile, BK=64, 4 waves; global_load_lds w=16, source-side XOR swizzle.
// EPI: 0 plain f16, 1 relu f16, 3 V->(B,NH,D,T) transposed, 4 fp32 store.
// ---------------------------------------------------------------------------
template <int EPI, bool CONCATA, bool NCHK>
__global__ __launch_bounds__(256) void mgemm(
    const f16* __restrict__ A, const f16* __restrict__ A2,
    const f16* __restrict__ Wt, const float* __restrict__ bias,
    const float* __restrict__ bias2, float scale, void* __restrict__ outp,
    int K, int N) {
  __shared__ f16 As[128 * 64];
  __shared__ f16 Bs[128 * 64];
  const int tid = threadIdx.x;
  const int lane = tid & 63, wid = tid >> 6;
  const int lq = lane & 15, lg = lane >> 4;
  const int wm = wid >> 1, wn = wid & 1;
  const int r0 = blockIdx.x * 128, c0 = blockIdx.y * 128;

  f32x4 acc[4][4] = {};

  for (int k0 = 0; k0 < K; k0 += 64) {
#pragma unroll
    for (int it = 0; it < 4; ++it) {
      const int off = it * 4096 + wid * 1024 + lane * 16;
      const int row = off >> 7;
      const int cb = (off >> 4) & 7;
      const int kc = k0 + ((cb ^ (row & 7)) << 3);
      const f16* src;
      if (CONCATA) {
        src = (kc < 512) ? (A + (size_t)(r0 + row) * 512 + kc)
                         : (A2 + (size_t)(r0 + row) * 512 + (kc - 512));
      } else {
        src = A + (size_t)(r0 + row) * K + kc;
      }
      gload_lds16(src, (f16*)((char*)As + off));
    }
#pragma unroll
    for (int it = 0; it < 4; ++it) {
      const int off = it * 4096 + wid * 1024 + lane * 16;
      const int row = off >> 7;
      const int cb = (off >> 4) & 7;
      int crow = c0 + row;
      if (NCHK) crow = crow < N ? crow : N - 1;
      gload_lds16(Wt + (size_t)crow * K + k0 + ((cb ^ (row & 7)) << 3),
                  (f16*)((char*)Bs + off));
    }
    __syncthreads();
#pragma unroll
    for (int kk = 0; kk < 2; ++kk) {
      f16x8 af[4], bf[4];
#pragma unroll
      for (int m = 0; m < 4; ++m) {
        const int row = wm * 64 + m * 16 + lq;
        af[m] = *(const f16x8*)((const char*)As + row * 128 +
                                (((kk * 4 + lg) ^ (row & 7)) << 4));
      }
#pragma unroll
      for (int n = 0; n < 4; ++n) {
        const int row = wn * 64 + n * 16 + lq;
        bf[n] = *(const f16x8*)((const char*)Bs + row * 128 +
                                (((kk * 4 + lg) ^ (row & 7)) << 4));
      }
#pragma unroll
      for (int m = 0; m < 4; ++m)
#pragma unroll
        for (int n = 0; n < 4; ++n) acc[m][n] = MFMA16(af[m], bf[n], acc[m][n]);
    }
    __syncthreads();
  }

  // epilogue — C/D layout: col = lane&15 (B-rows), row = (lane>>4)*4 + reg (A-rows)
#pragma unroll
  for (int m = 0; m < 4; ++m) {
    const int rbase = r0 + wm * 64 + m * 16 + lg * 4;
#pragma unroll
    for (int n = 0; n < 4; ++n) {
      const int col = c0 + wn * 64 + n * 16 + lq;
      if (NCHK && col >= N) continue;
      const float bsum = bias[col] + (bias2 ? bias2[col] : 0.f);
      const f32x4 a = acc[m][n];
      if (EPI == 3) {  // V: (B,NH,D,T)
        const int b = rbase >> 10, t = rbase & (T_ - 1);
        const int head = col >> 6, d = col & 63;
        f16x4 pk;
#pragma unroll
        for (int r = 0; r < 4; ++r) pk[r] = (f16)((a[r] + bsum) * scale);
        *(f16x4*)((f16*)outp + ((size_t)((b * NH_ + head) * D_ + d)) * T_ + t) =
            pk;
      } else {
#pragma unroll
        for (int r = 0; r < 4; ++r) {
          const int row = rbase + r;
          float v = (a[r] + bsum) * scale;
          if (EPI == 1) v = fmaxf(v, 0.f);
          if (EPI == 4)
            ((float*)outp)[(size_t)row * N + col] = v;
          else
            ((f16*)outp)[(size_t)row * N + col] = (f16)v;
        }
      }
    }
  }
}

// ---------------------------------------------------------------------------
// Flash attention v2 — all-swapped MFMA operands.
// Grid (T/128, NH, B); 4 waves x 32 q-rows (2 strips of 16). K/V tiles (64 k)
// staged to LDS (double-buffered) by all 4 waves via global_load_lds with
// source-side XOR swizzle; stage for kt+1 issued before compute of kt.
// QK^T: S^T = mfma(K, Q)  -> lane holds 16 k-vals for q = lane&15
//   => softmax m/l/corr are LANE-LOCAL; reduce = local 16 + shfl_xor(16,32).
// PV:   O^T = mfma(V^T, P) -> P re-enters as B-operand via per-wave 2KB LDS
//   (4x ds_write_b64 + 2x ds_read_b128 per strip, XOR-swizzled, 2-way free).
// O^T: row=d, col=q => rescale by corr is lane-uniform; store packs d x4.
// ---------------------------------------------------------------------------
__global__ __launch_bounds__(256) void attn_mfma2(
    const f16* __restrict__ q, const f16* __restrict__ k,
    const f16* __restrict__ vT, f16* __restrict__ ctx) {
  __shared__ f16 Ks[2][64 * 64];
  __shared__ f16 Vs[2][64 * 64];
  __shared__ f16 Ps[4][2][16 * 64];
  const int qt = blockIdx.x, head = blockIdx.y, b = blockIdx.z;
  const int tid = threadIdx.x, lane = tid & 63, wid = tid >> 6;
  const int lq = lane & 15, lg = lane >> 4;
  const int bh = b * NH_ + head;

  const f16* kbase = k + ((size_t)b * T_) * H_ + head * D_;
  const f16* vbase = vT + (size_t)bh * D_ * T_;

  auto stage = [&](int kt, int buf) {
#pragma unroll
    for (int it = 0; it < 2; ++it) {
      const int off = it * 4096 + tid * 16;  // LDS byte offset (linear dest)
      const int row = off >> 7;
      const int sc = ((((off >> 4) & 7) ^ (row & 7)) << 3);  // swizzled f16 col
      gload_lds16(kbase + (size_t)(kt * 64 + row) * H_ + sc,
                  (f16*)((char*)&Ks[buf][0] + off));
      gload_lds16(vbase + (size_t)row * T_ + kt * 64 + sc,
                  (f16*)((char*)&Vs[buf][0] + off));
    }
  };

  // Q B-fragments for both strips (held in regs all kernel)
  const int q0 = qt * 128 + wid * 32;
  f16x8 qf[2][2];
#pragma unroll
  for (int s = 0; s < 2; ++s)
#pragma unroll
    for (int kk = 0; kk < 2; ++kk)
      qf[s][kk] = *(const f16x8*)(q + ((size_t)(b * T_) + q0 + s * 16 + lq) * H_ +
                                  head * D_ + kk * 32 + lg * 8);

  float m_run[2] = {-1e30f, -1e30f}, l_run[2] = {0.f, 0.f};
  f32x4 accO[2][4] = {};

  stage(0, 0);
  __syncthreads();

  for (int kt = 0; kt < T_ / 64; ++kt) {
    const int cur = kt & 1;
    if (kt < T_ / 64 - 1) stage(kt + 1, cur ^ 1);  // overlap with compute

    // K fragments (A-operand): rows = k-local
    f16x8 kf[4][2];
#pragma unroll
    for (int n = 0; n < 4; ++n)
#pragma unroll
      for (int kk = 0; kk < 2; ++kk) {
        const int row = n * 16 + lq;
        kf[n][kk] = *(const f16x8*)((const char*)&Ks[cur][0] + row * 128 +
                                    (((kk * 4 + lg) ^ (row & 7)) << 4));
      }
    // S^T[k][q] strips
    f32x4 ssw[2][4] = {};
    __builtin_amdgcn_s_setprio(1);
#pragma unroll
    for (int s = 0; s < 2; ++s)
#pragma unroll
      for (int n = 0; n < 4; ++n)
#pragma unroll
        for (int kk = 0; kk < 2; ++kk)
          ssw[s][n] = MFMA16(kf[n][kk], qf[s][kk], ssw[s][n]);
    __builtin_amdgcn_s_setprio(0);

    // V^T fragments (A-operand): rows = d
    f16x8 vf[4][2];
#pragma unroll
    for (int n = 0; n < 4; ++n)
#pragma unroll
      for (int kk = 0; kk < 2; ++kk) {
        const int row = n * 16 + lq;
        vf[n][kk] = *(const f16x8*)((const char*)&Vs[cur][0] + row * 128 +
                                    (((kk * 4 + lg) ^ (row & 7)) << 4));
      }

    // online softmax — all per-lane (q = lq); reduce across the 4 lg lanes
#pragma unroll
    for (int s = 0; s < 2; ++s) {
      float mloc = -1e30f;
#pragma unroll
      for (int n = 0; n < 4; ++n)
#pragma unroll
        for (int r = 0; r < 4; ++r) mloc = fmaxf(mloc, ssw[s][n][r]);
      mloc = fmaxf(mloc, __shfl_xor(mloc, 16, 64));
      mloc = fmaxf(mloc, __shfl_xor(mloc, 32, 64));
      const float nm = fmaxf(m_run[s], mloc);
      const float corr = __expf(m_run[s] - nm);
      m_run[s] = nm;
      float sl = 0.f;
      char* pw = (char*)&Ps[wid][s][0] + lq * 128;
#pragma unroll
      for (int n = 0; n < 4; ++n) {
        f16x4 pk;
#pragma unroll
        for (int r = 0; r < 4; ++r) {
          const float p = __expf(ssw[s][n][r] - nm);
          sl += p;
          pk[r] = (f16)p;
        }
        *(f16x4*)(pw + ((n * 32 + lg * 8) ^ ((lq & 7) << 4))) = pk;
      }
      sl += __shfl_xor(sl, 16, 64);
      sl += __shfl_xor(sl, 32, 64);
      l_run[s] = l_run[s] * corr + sl;
#pragma unroll
      for (int n = 0; n < 4; ++n) {
        accO[s][n][0] *= corr; accO[s][n][1] *= corr;
        accO[s][n][2] *= corr; accO[s][n][3] *= corr;
      }
    }

    // P B-fragments
    f16x8 pb[2][2];
#pragma unroll
    for (int s = 0; s < 2; ++s)
#pragma unroll
      for (int kk = 0; kk < 2; ++kk)
        pb[s][kk] = *(const f16x8*)((const char*)&Ps[wid][s][0] + lq * 128 +
                                    ((((kk * 4 + lg) << 4)) ^ ((lq & 7) << 4)));
    __builtin_amdgcn_s_setprio(1);
#pragma unroll
    for (int s = 0; s < 2; ++s)
#pragma unroll
      for (int n = 0; n < 4; ++n)
#pragma unroll
        for (int kk = 0; kk < 2; ++kk)
          accO[s][n] = MFMA16(vf[n][kk], pb[s][kk], accO[s][n]);
    __builtin_amdgcn_s_setprio(0);
    __syncthreads();  // next stage may overwrite cur^1... all waves synced
  }

  // epilogue: O^T -> ctx (B,T,H); lane holds O[d=n*16+lg*4+r][q=q0+s*16+lq]
#pragma unroll
  for (int s = 0; s < 2; ++s) {
    const float inv = 1.f / l_run[s];
    const size_t rowoff = ((size_t)(b * T_) + q0 + s * 16 + lq) * H_ + head * D_;
#pragma unroll
    for (int n = 0; n < 4; ++n) {
      f16x4 o;
#pragma unroll
      for (int r = 0; r < 4; ++r) o[r] = (f16)(accO[s][n][r] * inv);
      *(f16x4*)(ctx + rowoff + n * 16 + lg * 4) = o;
    }
  }
}

// ---------------------------------------------------------------------------
// Conversions + small fused ops  [unchanged from R2]
// ---------------------------------------------------------------------------
__global__ void conv_f32_f16(const float* __restrict__ in, f16* __restrict__ out,
                             int n4) {
  const int i = blockIdx.x * blockDim.x + threadIdx.x;
  if (i >= n4) return;
  const float4 v = ((const float4*)in)[i];
  f16x4 o = {(f16)v.x, (f16)v.y, (f16)v.z, (f16)v.w};
  ((f16x4*)out)[i] = o;
}

__global__ void build_pm(const float* __restrict__ tmel, f16* __restrict__ pm) {
  const int i = blockIdx.x * blockDim.x + threadIdx.x;
  const int r = i >> 5, c4 = (i & 31) * 4;
  const int t = r & (T_ - 1);
  f16x4 o = {};
  if (t != 0 && c4 < M_) {
    const float4 v = *(const float4*)(tmel + (size_t)(r - 1) * M_ + c4);
    o = {(f16)v.x, (f16)v.y, (f16)v.z, (f16)v.w};
  }
  *(f16x4*)(pm + (size_t)r * 128 + c4) = o;
}

__global__ void build_wp(const float* __restrict__ w, f16* __restrict__ wp) {
  const int i = blockIdx.x * blockDim.x + threadIdx.x;
  const int r = i >> 5, c4 = (i & 31) * 4;
  f16x4 o = {};
  if (c4 < M_) {
    const float4 v = *(const float4*)(w + (size_t)r * M_ + c4);
    o = {(f16)v.x, (f16)v.y, (f16)v.z, (f16)v.w};
  }
  *(f16x4*)(wp + (size_t)r * 128 + c4) = o;
}

__global__ void lstm_combine(const f16* __restrict__ gi, const f16* __restrict__ gg,
                             const f16* __restrict__ go, f16* __restrict__ h,
                             int n8) {
  const int i = blockIdx.x * blockDim.x + threadIdx.x;
  if (i >= n8) return;
  const f16x8 vi = ((const f16x8*)gi)[i];
  const f16x8 vg = ((const f16x8*)gg)[i];
  const f16x8 vo = ((const f16x8*)go)[i];
  f16x8 r;
#pragma unroll
  for (int j = 0; j < 8; ++j) {
    const float xi = (float)vi[j], xg = (float)vg[j], xo = (float)vo[j];
    const float si = 1.f / (1.f + __expf(-xi));
    const float so = 1.f / (1.f + __expf(-xo));
    const float tg = 2.f / (1.f + __expf(-2.f * xg)) - 1.f;
    const float c = si * tg;
    const float tc = 2.f / (1.f + __expf(-2.f * c)) - 1.f;
    r[j] = (f16)(so * tc);
  }
  ((f16x8*)h)[i] = r;
}

// ---------------------------------------------------------------------------
extern "C" void kernel_launch(void* const* d_in, const int* in_sizes, int n_in,
                              void* d_out, int out_size, void* d_ws,
                              size_t ws_size, hipStream_t stream) {
  const float* enc = (const float*)d_in[0];
  const float* tmel = (const float*)d_in[1];
  const float* w_pre = (const float*)d_in[2];
  const float* b_pre = (const float*)d_in[3];
  const float* inw = (const float*)d_in[4];
  const float* inb = (const float*)d_in[5];
  const float* outw = (const float*)d_in[6];
  const float* outb = (const float*)d_in[7];
  const float* wih0 = (const float*)d_in[8];
  const float* bih0 = (const float*)d_in[10];
  const float* bhh0 = (const float*)d_in[11];
  const float* wih1 = (const float*)d_in[12];
  const float* bih1 = (const float*)d_in[14];
  const float* bhh1 = (const float*)d_in[15];
  const float* wmel = (const float*)d_in[16];
  const float* bmel = (const float*)d_in[17];

  f16* wsh = (f16*)d_ws;
  const size_t SEG = (size_t)N_ * H_;  // 8388608 f16 per slot (16.8 MB)
  f16* EncB = wsh;                     // S0; reused as aout
  f16* h1 = wsh + SEG;                 // S1
  f16* pre = wsh + 2 * SEG;            // S2
  f16* qb = wsh + 3 * SEG;             // S3; reused as h2
  f16* kbuf = wsh + 4 * SEG;           // S4; reused as gate i
  f16* vTb = wsh + 5 * SEG;            // S5; reused as gate g
  f16* ctx = wsh + 6 * SEG;            // S6; reused as gate o
  f16* aout = EncB;
  f16* gi = kbuf;
  f16* gg = vTb;
  f16* go = ctx;
  f16* h2 = qb;
  f16* WP = wsh + 7 * SEG;
  f16* WIN = WP + 512 * 128;
  f16* WOUT = WIN + 1536 * 512;
  f16* WIH0 = WOUT + 512 * 512;
  f16* WIH1 = WIH0 + 2048 * 1024;
  f16* WMEL = WIH1 + 2048 * 512;
  f16* PM = WMEL + 80 * 512;

  const dim3 blk(256);
  auto cv = [&](const float* s, f16* d, int n) {
    conv_f32_f16<<<(n / 4 + 255) / 256, blk, 0, stream>>>(s, d, n / 4);
  };
  cv(enc, EncB, N_ * H_);
  cv(inw, WIN, 1536 * 512);
  cv(outw, WOUT, 512 * 512);
  cv(wih0, WIH0, 2048 * 1024);
  cv(wih1, WIH1, 2048 * 512);
  cv(wmel, WMEL, 80 * 512);
  build_pm<<<(N_ * 32) / 256, blk, 0, stream>>>(tmel, PM);
  build_wp<<<(512 * 32) / 256, blk, 0, stream>>>(w_pre, WP);

  const dim3 g512(N_ / 128, 4), g80(N_ / 128, 1);
  mgemm<1, false, false><<<g512, blk, 0, stream>>>(PM, nullptr, WP, b_pre,
                                                   nullptr, 1.f, pre, 128, 512);
  mgemm<0, false, false><<<g512, blk, 0, stream>>>(pre, nullptr, WIN, inb,
                                                   nullptr, 0.125f, qb, 512, 512);
  mgemm<0, false, false><<<g512, blk, 0, stream>>>(
      EncB, nullptr, WIN + 512 * 512, inb + 512, nullptr, 1.f, kbuf, 512, 512);
  mgemm<3, false, false><<<g512, blk, 0, stream>>>(
      EncB, nullptr, WIN + 1024 * 512, inb + 1024, nullptr, 1.f, vTb, 512, 512);
  attn_mfma2<<<dim3(T_ / 128, NH_, B_), blk, 0, stream>>>(qb, kbuf, vTb, ctx);
  mgemm<0, false, false><<<g512, blk, 0, stream>>>(ctx, nullptr, WOUT, outb,
                                                   nullptr, 1.f, aout, 512, 512);
  mgemm<0, true, false><<<g512, blk, 0, stream>>>(
      pre, aout, WIH0, bih0, bhh0, 1.f, gi, 1024, 512);
  mgemm<0, true, false><<<g512, blk, 0, stream>>>(
      pre, aout, WIH0 + (size_t)1024 * 1024, bih0 + 1024, bhh0 + 1024, 1.f, gg,
      1024, 512);
  mgemm<0, true, false><<<g512, blk, 0, stream>>>(
      pre, aout, WIH0 + (size_t)1536 * 1024, bih0 + 1536, bhh0 + 1536, 1.f, go,
      1024, 512);
  lstm_combine<<<(int)(SEG / 8 + 255) / 256, blk, 0, stream>>>(gi, gg, go, h1,
                                                               (int)(SEG / 8));
  mgemm<0, false, false><<<g512, blk, 0, stream>>>(h1, nullptr, WIH1, bih1,
                                                   bhh1, 1.f, gi, 512, 512);
  mgemm<0, false, false><<<g512, blk, 0, stream>>>(
      h1, nullptr, WIH1 + (size_t)1024 * 512, bih1 + 1024, bhh1 + 1024, 1.f, gg,
      512, 512);
  mgemm<0, false, false><<<g512, blk, 0, stream>>>(
      h1, nullptr, WIH1 + (size_t)1536 * 512, bih1 + 1536, bhh1 + 1536, 1.f, go,
      512, 512);
  lstm_combine<<<(int)(SEG / 8 + 255) / 256, blk, 0, stream>>>(gi, gg, go, h2,
                                                               (int)(SEG / 8));
  mgemm<4, false, true><<<g80, blk, 0, stream>>>(h2, nullptr, WMEL, bmel,
                                                 nullptr, 1.f, (float*)d_out,
                                                 512, 80);
}

// Round 5
// 308.467 us; speedup vs baseline: 8.5829x; 1.1806x over previous
//
#include <hip/hip_runtime.h>

// Tacotron2 decoder — round 5.
// R1 fp32 2647us -> R2 fp16 MFMA 512us -> R3 attn swap/stage 364us.
// R4 FAILED: shared-P refactor dropped the lq*128 row offset in the P
//   write/read (read had literal `lq*0`) -> all q-rows collided in row 0.
// R5: restore row offset; keep R4's occupancy fix (40KB LDS), bijective
//   psw swizzle (bits 5-6), defer-max, fused 3-gate LSTM, merged convs.

typedef _Float16 f16;
typedef _Float16 f16x8 __attribute__((ext_vector_type(8)));
typedef _Float16 f16x4 __attribute__((ext_vector_type(4)));
typedef float f32x4 __attribute__((ext_vector_type(4)));

constexpr int B_ = 16, T_ = 1024, H_ = 512, M_ = 80;
constexpr int NH_ = 8, D_ = 64;
constexpr int N_ = B_ * T_;  // 16384 rows

#define MFMA16(a, b, c) __builtin_amdgcn_mfma_f32_16x16x32_f16(a, b, c, 0, 0, 0)

__device__ __forceinline__ void gload_lds16(const f16* g, f16* l) {
  __builtin_amdgcn_global_load_lds(
      (const __attribute__((address_space(1))) void*)g,
      (__attribute__((address_space(3))) void*)l, 16, 0, 0);
}

// ---------------------------------------------------------------------------
// MFMA GEMM [validated R2/R3, unchanged]: C = epi((A@Wt^T + bias[+bias2])*scale)
// 128x128 tile, BK=64, 4 waves; global_load_lds w=16, source-side XOR swizzle.
// EPI: 0 plain f16, 1 relu f16, 3 V->(B,NH,D,T) transposed, 4 fp32 store.
// ---------------------------------------------------------------------------
template <int EPI, bool CONCATA, bool NCHK>
__global__ __launch_bounds__(256) void mgemm(
    const f16* __restrict__ A, const f16* __restrict__ A2,
    const f16* __restrict__ Wt, const float* __restrict__ bias,
    const float* __restrict__ bias2, float scale, void* __restrict__ outp,
    int K, int N) {
  __shared__ f16 As[128 * 64];
  __shared__ f16 Bs[128 * 64];
  const int tid = threadIdx.x;
  const int lane = tid & 63, wid = tid >> 6;
  const int lq = lane & 15, lg = lane >> 4;
  const int wm = wid >> 1, wn = wid & 1;
  const int r0 = blockIdx.x * 128, c0 = blockIdx.y * 128;

  f32x4 acc[4][4] = {};

  for (int k0 = 0; k0 < K; k0 += 64) {
#pragma unroll
    for (int it = 0; it < 4; ++it) {
      const int off = it * 4096 + wid * 1024 + lane * 16;
      const int row = off >> 7;
      const int cb = (off >> 4) & 7;
      const int kc = k0 + ((cb ^ (row & 7)) << 3);
      const f16* src;
      if (CONCATA) {
        src = (kc < 512) ? (A + (size_t)(r0 + row) * 512 + kc)
                         : (A2 + (size_t)(r0 + row) * 512 + (kc - 512));
      } else {
        src = A + (size_t)(r0 + row) * K + kc;
      }
      gload_lds16(src, (f16*)((char*)As + off));
    }
#pragma unroll
    for (int it = 0; it < 4; ++it) {
      const int off = it * 4096 + wid * 1024 + lane * 16;
      const int row = off >> 7;
      const int cb = (off >> 4) & 7;
      int crow = c0 + row;
      if (NCHK) crow = crow < N ? crow : N - 1;
      gload_lds16(Wt + (size_t)crow * K + k0 + ((cb ^ (row & 7)) << 3),
                  (f16*)((char*)Bs + off));
    }
    __syncthreads();
#pragma unroll
    for (int kk = 0; kk < 2; ++kk) {
      f16x8 af[4], bf[4];
#pragma unroll
      for (int m = 0; m < 4; ++m) {
        const int row = wm * 64 + m * 16 + lq;
        af[m] = *(const f16x8*)((const char*)As + row * 128 +
                                (((kk * 4 + lg) ^ (row & 7)) << 4));
      }
#pragma unroll
      for (int n = 0; n < 4; ++n) {
        const int row = wn * 64 + n * 16 + lq;
        bf[n] = *(const f16x8*)((const char*)Bs + row * 128 +
                                (((kk * 4 + lg) ^ (row & 7)) << 4));
      }
#pragma unroll
      for (int m = 0; m < 4; ++m)
#pragma unroll
        for (int n = 0; n < 4; ++n) acc[m][n] = MFMA16(af[m], bf[n], acc[m][n]);
    }
    __syncthreads();
  }

#pragma unroll
  for (int m = 0; m < 4; ++m) {
    const int rbase = r0 + wm * 64 + m * 16 + lg * 4;
#pragma unroll
    for (int n = 0; n < 4; ++n) {
      const int col = c0 + wn * 64 + n * 16 + lq;
      if (NCHK && col >= N) continue;
      const float bsum = bias[col] + (bias2 ? bias2[col] : 0.f);
      const f32x4 a = acc[m][n];
      if (EPI == 3) {  // V: (B,NH,D,T)
        const int b = rbase >> 10, t = rbase & (T_ - 1);
        const int head = col >> 6, d = col & 63;
        f16x4 pk;
#pragma unroll
        for (int r = 0; r < 4; ++r) pk[r] = (f16)((a[r] + bsum) * scale);
        *(f16x4*)((f16*)outp + ((size_t)((b * NH_ + head) * D_ + d)) * T_ + t) =
            pk;
      } else {
#pragma unroll
        for (int r = 0; r < 4; ++r) {
          const int row = rbase + r;
          float v = (a[r] + bsum) * scale;
          if (EPI == 1) v = fmaxf(v, 0.f);
          if (EPI == 4)
            ((float*)outp)[(size_t)row * N + col] = v;
          else
            ((f16*)outp)[(size_t)row * N + col] = (f16)v;
        }
      }
    }
  }
}

// ---------------------------------------------------------------------------
// Fused zero-state LSTM [R4 structure]: h = sig(o)*tanh(sig(i)*tanh(g)).
// 128x128x3-gate tile, 8 waves (4m x 2n), A staged once, combine in epilogue.
// ---------------------------------------------------------------------------
template <bool CONCATA>
__global__ __launch_bounds__(512) void lstm_fused(
    const f16* __restrict__ A, const f16* __restrict__ A2,
    const f16* __restrict__ Wih, const float* __restrict__ bih,
    const float* __restrict__ bhh, f16* __restrict__ Hout_) {
  constexpr int K = CONCATA ? 1024 : 512;
  __shared__ f16 As[128 * 64];
  __shared__ f16 Bs[3][128 * 64];
  const int tid = threadIdx.x;
  const int lane = tid & 63, wid = tid >> 6;  // 8 waves
  const int lq = lane & 15, lg = lane >> 4;
  const int wm = wid >> 1, wn = wid & 1;  // 4m x 2n
  const int r0 = blockIdx.x * 128, c0 = blockIdx.y * 128;

  f32x4 acc[3][2][4] = {};

  for (int k0 = 0; k0 < K; k0 += 64) {
#pragma unroll
    for (int it = 0; it < 2; ++it) {
      const int off = it * 8192 + tid * 16;
      const int row = off >> 7;
      const int cb = (off >> 4) & 7;
      const int kc = k0 + ((cb ^ (row & 7)) << 3);
      const f16* src;
      if (CONCATA) {
        src = (kc < 512) ? (A + (size_t)(r0 + row) * 512 + kc)
                         : (A2 + (size_t)(r0 + row) * 512 + (kc - 512));
      } else {
        src = A + (size_t)(r0 + row) * K + kc;
      }
      gload_lds16(src, (f16*)((char*)As + off));
    }
#pragma unroll
    for (int g = 0; g < 3; ++g) {
      const int gbase = (g == 0) ? 0 : 512 * (g + 1);  // i=0, g=1024, o=1536
#pragma unroll
      for (int it = 0; it < 2; ++it) {
        const int off = it * 8192 + tid * 16;
        const int row = off >> 7;
        const int cb = (off >> 4) & 7;
        gload_lds16(
            Wih + (size_t)(gbase + c0 + row) * K + k0 + ((cb ^ (row & 7)) << 3),
            (f16*)((char*)&Bs[g][0] + off));
      }
    }
    __syncthreads();
#pragma unroll
    for (int kk = 0; kk < 2; ++kk) {
      f16x8 af[2];
#pragma unroll
      for (int m = 0; m < 2; ++m) {
        const int row = wm * 32 + m * 16 + lq;
        af[m] = *(const f16x8*)((const char*)As + row * 128 +
                                (((kk * 4 + lg) ^ (row & 7)) << 4));
      }
#pragma unroll
      for (int g = 0; g < 3; ++g)
#pragma unroll
        for (int n = 0; n < 4; ++n) {
          const int row = wn * 64 + n * 16 + lq;
          const f16x8 bf = *(const f16x8*)((const char*)&Bs[g][0] + row * 128 +
                                           (((kk * 4 + lg) ^ (row & 7)) << 4));
#pragma unroll
          for (int m = 0; m < 2; ++m)
            acc[g][m][n] = MFMA16(af[m], bf, acc[g][m][n]);
        }
    }
    __syncthreads();
  }

#pragma unroll
  for (int n = 0; n < 4; ++n) {
    const int c = c0 + wn * 64 + n * 16 + lq;
    const float bi = bih[c] + bhh[c];
    const float bg = bih[1024 + c] + bhh[1024 + c];
    const float bo = bih[1536 + c] + bhh[1536 + c];
#pragma unroll
    for (int m = 0; m < 2; ++m) {
      const int rbase = r0 + wm * 32 + m * 16 + lg * 4;
#pragma unroll
      for (int r = 0; r < 4; ++r) {
        const float gi = acc[0][m][n][r] + bi;
        const float gg = acc[1][m][n][r] + bg;
        const float go = acc[2][m][n][r] + bo;
        const float si = 1.f / (1.f + __expf(-gi));
        const float so = 1.f / (1.f + __expf(-go));
        const float tg = 2.f / (1.f + __expf(-2.f * gg)) - 1.f;
        const float cc = si * tg;
        const float tc = 2.f / (1.f + __expf(-2.f * cc)) - 1.f;
        Hout_[(size_t)(rbase + r) * 512 + c] = (f16)(so * tc);
      }
    }
  }
}

// ---------------------------------------------------------------------------
// Flash attention v3 (R4 structure, P row offset FIXED).
// P buffer: per-wave 16 rows x 128B; row = lq; psw XORs bits 5-6 only
// (disjoint from write-granule bits 3-4 and row bits 7+ -> bijective).
// ---------------------------------------------------------------------------
__global__ __launch_bounds__(256) void attn_mfma3(
    const f16* __restrict__ q, const f16* __restrict__ k,
    const f16* __restrict__ vT, f16* __restrict__ ctx) {
  __shared__ f16 Ks[2][64 * 64];
  __shared__ f16 Vs[2][64 * 64];
  __shared__ f16 Ps[4][16 * 64];  // one strip per wave, reused
  const int qt = blockIdx.x, head = blockIdx.y, b = blockIdx.z;
  const int tid = threadIdx.x, lane = tid & 63, wid = tid >> 6;
  const int lq = lane & 15, lg = lane >> 4;
  const int bh = b * NH_ + head;

  const f16* kbase = k + ((size_t)b * T_) * H_ + head * D_;
  const f16* vbase = vT + (size_t)bh * D_ * T_;

  auto stage = [&](int kt, int buf) {
#pragma unroll
    for (int it = 0; it < 2; ++it) {
      const int off = it * 4096 + tid * 16;
      const int row = off >> 7;
      const int sc = ((((off >> 4) & 7) ^ (row & 7)) << 3);
      gload_lds16(kbase + (size_t)(kt * 64 + row) * H_ + sc,
                  (f16*)((char*)&Ks[buf][0] + off));
      gload_lds16(vbase + (size_t)row * T_ + kt * 64 + sc,
                  (f16*)((char*)&Vs[buf][0] + off));
    }
  };

  const int q0 = qt * 128 + wid * 32;
  f16x8 qf[2][2];
#pragma unroll
  for (int s = 0; s < 2; ++s)
#pragma unroll
    for (int kk = 0; kk < 2; ++kk)
      qf[s][kk] = *(const f16x8*)(q + ((size_t)(b * T_) + q0 + s * 16 + lq) * H_ +
                                  head * D_ + kk * 32 + lg * 8);

  float m_run[2] = {-1e30f, -1e30f}, l_run[2] = {0.f, 0.f};
  f32x4 accO[2][4] = {};
  char* pw = (char*)&Ps[wid][0] + lq * 128;  // R4 bug: this offset was missing
  const int psw = (lq & 3) << 5;  // XOR bits 5-6 only

  stage(0, 0);
  __syncthreads();

  for (int kt = 0; kt < T_ / 64; ++kt) {
    const int cur = kt & 1;
    if (kt < T_ / 64 - 1) stage(kt + 1, cur ^ 1);

    // K fragments (A-operand)
    f16x8 kf[4][2];
#pragma unroll
    for (int n = 0; n < 4; ++n)
#pragma unroll
      for (int kk = 0; kk < 2; ++kk) {
        const int row = n * 16 + lq;
        kf[n][kk] = *(const f16x8*)((const char*)&Ks[cur][0] + row * 128 +
                                    (((kk * 4 + lg) ^ (row & 7)) << 4));
      }
    // S^T strips = mfma(K, Q)
    f32x4 ssw[2][4] = {};
    __builtin_amdgcn_s_setprio(1);
#pragma unroll
    for (int s = 0; s < 2; ++s)
#pragma unroll
      for (int n = 0; n < 4; ++n)
#pragma unroll
        for (int kk = 0; kk < 2; ++kk)
          ssw[s][n] = MFMA16(kf[n][kk], qf[s][kk], ssw[s][n]);
    __builtin_amdgcn_s_setprio(0);

    // V^T fragments (A-operand)
    f16x8 vf[4][2];
#pragma unroll
    for (int n = 0; n < 4; ++n)
#pragma unroll
      for (int kk = 0; kk < 2; ++kk) {
        const int row = n * 16 + lq;
        vf[n][kk] = *(const f16x8*)((const char*)&Vs[cur][0] + row * 128 +
                                    (((kk * 4 + lg) ^ (row & 7)) << 4));
      }

    // per-strip: online softmax (defer-max) -> P via LDS -> PV
#pragma unroll
    for (int s = 0; s < 2; ++s) {
      float mloc = -1e30f;
#pragma unroll
      for (int n = 0; n < 4; ++n)
#pragma unroll
        for (int r = 0; r < 4; ++r) mloc = fmaxf(mloc, ssw[s][n][r]);
      mloc = fmaxf(mloc, __shfl_xor(mloc, 16, 64));
      mloc = fmaxf(mloc, __shfl_xor(mloc, 32, 64));

      const bool noresc = __all(mloc - m_run[s] <= 8.f);
      if (!noresc) {
        const float nm = fmaxf(m_run[s], mloc);
        const float corr = __expf(m_run[s] - nm);
        m_run[s] = nm;
        l_run[s] *= corr;
#pragma unroll
        for (int n = 0; n < 4; ++n) {
          accO[s][n][0] *= corr; accO[s][n][1] *= corr;
          accO[s][n][2] *= corr; accO[s][n][3] *= corr;
        }
      }
      float sl = 0.f;
#pragma unroll
      for (int n = 0; n < 4; ++n) {
        f16x4 pk;
#pragma unroll
        for (int r = 0; r < 4; ++r) {
          const float p = __expf(ssw[s][n][r] - m_run[s]);
          sl += p;
          pk[r] = (f16)p;
        }
        *(f16x4*)(pw + ((n * 32 + lg * 8) ^ psw)) = pk;
      }
      sl += __shfl_xor(sl, 16, 64);
      sl += __shfl_xor(sl, 32, 64);
      l_run[s] += sl;

      f16x8 pb[2];
#pragma unroll
      for (int kk = 0; kk < 2; ++kk)
        pb[kk] = *(const f16x8*)(pw + ((((kk * 4 + lg) << 4)) ^ psw));
      __builtin_amdgcn_s_setprio(1);
#pragma unroll
      for (int n = 0; n < 4; ++n)
#pragma unroll
        for (int kk = 0; kk < 2; ++kk)
          accO[s][n] = MFMA16(vf[n][kk], pb[kk], accO[s][n]);
      __builtin_amdgcn_s_setprio(0);
    }
    __syncthreads();
  }

  // epilogue: O^T -> ctx; lane holds O[d=n*16+lg*4+r][q=q0+s*16+lq]
#pragma unroll
  for (int s = 0; s < 2; ++s) {
    const float inv = 1.f / l_run[s];
    const size_t rowoff = ((size_t)(b * T_) + q0 + s * 16 + lq) * H_ + head * D_;
#pragma unroll
    for (int n = 0; n < 4; ++n) {
      f16x4 o;
#pragma unroll
      for (int r = 0; r < 4; ++r) o[r] = (f16)(accO[s][n][r] * inv);
      *(f16x4*)(ctx + rowoff + n * 16 + lg * 4) = o;
    }
  }
}

// ---------------------------------------------------------------------------
// Merged conversions + small builders
// ---------------------------------------------------------------------------
constexpr int C0 = 2097152;            // enc    (8.4M f32 / 4)
constexpr int C1 = C0 + 196608;        // inw
constexpr int C2 = C1 + 65536;         // outw
constexpr int C3 = C2 + 524288;        // wih0
constexpr int C4 = C3 + 262144;        // wih1
constexpr int C5 = C4 + 10240;         // wmel
__global__ void conv_all(const float* __restrict__ enc, const float* __restrict__ inw,
                         const float* __restrict__ outw, const float* __restrict__ wih0,
                         const float* __restrict__ wih1, const float* __restrict__ wmel,
                         f16* denc, f16* dinw, f16* doutw, f16* dwih0,
                         f16* dwih1, f16* dwmel) {
  const int i = blockIdx.x * blockDim.x + threadIdx.x;
  const float* s;
  f16* d;
  int off;
  if (i < C0) { s = enc; d = denc; off = i; }
  else if (i < C1) { s = inw; d = dinw; off = i - C0; }
  else if (i < C2) { s = outw; d = doutw; off = i - C1; }
  else if (i < C3) { s = wih0; d = dwih0; off = i - C2; }
  else if (i < C4) { s = wih1; d = dwih1; off = i - C3; }
  else if (i < C5) { s = wmel; d = dwmel; off = i - C4; }
  else return;
  const float4 v = ((const float4*)s)[off];
  f16x4 o = {(f16)v.x, (f16)v.y, (f16)v.z, (f16)v.w};
  ((f16x4*)d)[off] = o;
}

__global__ void build_pm(const float* __restrict__ tmel, f16* __restrict__ pm) {
  const int i = blockIdx.x * blockDim.x + threadIdx.x;
  const int r = i >> 5, c4 = (i & 31) * 4;
  const int t = r & (T_ - 1);
  f16x4 o = {};
  if (t != 0 && c4 < M_) {
    const float4 v = *(const float4*)(tmel + (size_t)(r - 1) * M_ + c4);
    o = {(f16)v.x, (f16)v.y, (f16)v.z, (f16)v.w};
  }
  *(f16x4*)(pm + (size_t)r * 128 + c4) = o;
}

__global__ void build_wp(const float* __restrict__ w, f16* __restrict__ wp) {
  const int i = blockIdx.x * blockDim.x + threadIdx.x;
  const int r = i >> 5, c4 = (i & 31) * 4;
  f16x4 o = {};
  if (c4 < M_) {
    const float4 v = *(const float4*)(w + (size_t)r * M_ + c4);
    o = {(f16)v.x, (f16)v.y, (f16)v.z, (f16)v.w};
  }
  *(f16x4*)(wp + (size_t)r * 128 + c4) = o;
}

// ---------------------------------------------------------------------------
extern "C" void kernel_launch(void* const* d_in, const int* in_sizes, int n_in,
                              void* d_out, int out_size, void* d_ws,
                              size_t ws_size, hipStream_t stream) {
  const float* enc = (const float*)d_in[0];
  const float* tmel = (const float*)d_in[1];
  const float* w_pre = (const float*)d_in[2];
  const float* b_pre = (const float*)d_in[3];
  const float* inw = (const float*)d_in[4];
  const float* inb = (const float*)d_in[5];
  const float* outw = (const float*)d_in[6];
  const float* outb = (const float*)d_in[7];
  const float* wih0 = (const float*)d_in[8];
  const float* bih0 = (const float*)d_in[10];
  const float* bhh0 = (const float*)d_in[11];
  const float* wih1 = (const float*)d_in[12];
  const float* bih1 = (const float*)d_in[14];
  const float* bhh1 = (const float*)d_in[15];
  const float* wmel = (const float*)d_in[16];
  const float* bmel = (const float*)d_in[17];

  f16* wsh = (f16*)d_ws;
  const size_t SEG = (size_t)N_ * H_;  // 8388608 f16 per slot
  f16* EncB = wsh;                     // S0; reused as aout
  f16* h1 = wsh + SEG;                 // S1
  f16* pre = wsh + 2 * SEG;            // S2
  f16* qb = wsh + 3 * SEG;             // S3; reused as h2
  f16* kbuf = wsh + 4 * SEG;           // S4
  f16* vTb = wsh + 5 * SEG;            // S5
  f16* ctx = wsh + 6 * SEG;            // S6
  f16* aout = EncB;
  f16* h2 = qb;
  f16* WP = wsh + 7 * SEG;
  f16* WIN = WP + 512 * 128;
  f16* WOUT = WIN + 1536 * 512;
  f16* WIH0 = WOUT + 512 * 512;
  f16* WIH1 = WIH0 + 2048 * 1024;
  f16* WMEL = WIH1 + 2048 * 512;
  f16* PM = WMEL + 80 * 512;

  const dim3 blk(256);
  conv_all<<<(C5 + 255) / 256, blk, 0, stream>>>(enc, inw, outw, wih0, wih1,
                                                 wmel, EncB, WIN, WOUT, WIH0,
                                                 WIH1, WMEL);
  build_pm<<<(N_ * 32) / 256, blk, 0, stream>>>(tmel, PM);
  build_wp<<<(512 * 32) / 256, blk, 0, stream>>>(w_pre, WP);

  const dim3 g512(N_ / 128, 4), g80(N_ / 128, 1);
  mgemm<1, false, false><<<g512, blk, 0, stream>>>(PM, nullptr, WP, b_pre,
                                                   nullptr, 1.f, pre, 128, 512);
  mgemm<0, false, false><<<g512, blk, 0, stream>>>(pre, nullptr, WIN, inb,
                                                   nullptr, 0.125f, qb, 512, 512);
  mgemm<0, false, false><<<g512, blk, 0, stream>>>(
      EncB, nullptr, WIN + 512 * 512, inb + 512, nullptr, 1.f, kbuf, 512, 512);
  mgemm<3, false, false><<<g512, blk, 0, stream>>>(
      EncB, nullptr, WIN + 1024 * 512, inb + 1024, nullptr, 1.f, vTb, 512, 512);
  attn_mfma3<<<dim3(T_ / 128, NH_, B_), blk, 0, stream>>>(qb, kbuf, vTb, ctx);
  mgemm<0, false, false><<<g512, blk, 0, stream>>>(ctx, nullptr, WOUT, outb,
                                                   nullptr, 1.f, aout, 512, 512);
  // fused LSTMs (gates i/g/o + combine in-kernel; f and W_hh dead at zero state)
  lstm_fused<true><<<dim3(N_ / 128, 4), dim3(512), 0, stream>>>(
      pre, aout, WIH0, bih0, bhh0, h1);
  lstm_fused<false><<<dim3(N_ / 128, 4), dim3(512), 0, stream>>>(
      h1, nullptr, WIH1, bih1, bhh1, h2);
  mgemm<4, false, true><<<g80, blk, 0, stream>>>(h2, nullptr, WMEL, bmel,
                                                 nullptr, 1.f, (float*)d_out,
                                                 512, 80);
}

// Round 6
// 285.662 us; speedup vs baseline: 9.2680x; 1.0798x over previous
//
#include <hip/hip_runtime.h>

// Tacotron2 decoder — round 6.
// R1 fp32 2647 -> R2 MFMA 512 -> R3 attn-swap 364 -> R5 fusion 308us.
// R5 counters: lstm_fused<1> 85.6us, MfmaUtil 24%, LDS-read-bound
//   (28 ds_read_b128 per 48 MFMA per wave per K-step).
// R6: (a) lstm_fused v2 — 4 waves x 64x64 wave-tile (acc[3][4][4]), ratio
//     32 reads : 96 MFMAs; (b) kv_fused — k+v projections share one enc
//     staging (2-gate kernel, k->(B,T,H), v->(B,NH,D,T)).

typedef _Float16 f16;
typedef _Float16 f16x8 __attribute__((ext_vector_type(8)));
typedef _Float16 f16x4 __attribute__((ext_vector_type(4)));
typedef float f32x4 __attribute__((ext_vector_type(4)));

constexpr int B_ = 16, T_ = 1024, H_ = 512, M_ = 80;
constexpr int NH_ = 8, D_ = 64;
constexpr int N_ = B_ * T_;  // 16384 rows

#define MFMA16(a, b, c) __builtin_amdgcn_mfma_f32_16x16x32_f16(a, b, c, 0, 0, 0)

__device__ __forceinline__ void gload_lds16(const f16* g, f16* l) {
  __builtin_amdgcn_global_load_lds(
      (const __attribute__((address_space(1))) void*)g,
      (__attribute__((address_space(3))) void*)l, 16, 0, 0);
}

// ---------------------------------------------------------------------------
// MFMA GEMM [validated R2-R5, unchanged]: C = epi((A@Wt^T + bias[+bias2])*scale)
// 128x128 tile, BK=64, 4 waves; global_load_lds w=16, source-side XOR swizzle.
// EPI: 0 plain f16, 1 relu f16, 3 V->(B,NH,D,T) transposed, 4 fp32 store.
// ---------------------------------------------------------------------------
template <int EPI, bool CONCATA, bool NCHK>
__global__ __launch_bounds__(256) void mgemm(
    const f16* __restrict__ A, const f16* __restrict__ A2,
    const f16* __restrict__ Wt, const float* __restrict__ bias,
    const float* __restrict__ bias2, float scale, void* __restrict__ outp,
    int K, int N) {
  __shared__ f16 As[128 * 64];
  __shared__ f16 Bs[128 * 64];
  const int tid = threadIdx.x;
  const int lane = tid & 63, wid = tid >> 6;
  const int lq = lane & 15, lg = lane >> 4;
  const int wm = wid >> 1, wn = wid & 1;
  const int r0 = blockIdx.x * 128, c0 = blockIdx.y * 128;

  f32x4 acc[4][4] = {};

  for (int k0 = 0; k0 < K; k0 += 64) {
#pragma unroll
    for (int it = 0; it < 4; ++it) {
      const int off = it * 4096 + wid * 1024 + lane * 16;
      const int row = off >> 7;
      const int cb = (off >> 4) & 7;
      const int kc = k0 + ((cb ^ (row & 7)) << 3);
      const f16* src;
      if (CONCATA) {
        src = (kc < 512) ? (A + (size_t)(r0 + row) * 512 + kc)
                         : (A2 + (size_t)(r0 + row) * 512 + (kc - 512));
      } else {
        src = A + (size_t)(r0 + row) * K + kc;
      }
      gload_lds16(src, (f16*)((char*)As + off));
    }
#pragma unroll
    for (int it = 0; it < 4; ++it) {
      const int off = it * 4096 + wid * 1024 + lane * 16;
      const int row = off >> 7;
      const int cb = (off >> 4) & 7;
      int crow = c0 + row;
      if (NCHK) crow = crow < N ? crow : N - 1;
      gload_lds16(Wt + (size_t)crow * K + k0 + ((cb ^ (row & 7)) << 3),
                  (f16*)((char*)Bs + off));
    }
    __syncthreads();
#pragma unroll
    for (int kk = 0; kk < 2; ++kk) {
      f16x8 af[4], bf[4];
#pragma unroll
      for (int m = 0; m < 4; ++m) {
        const int row = wm * 64 + m * 16 + lq;
        af[m] = *(const f16x8*)((const char*)As + row * 128 +
                                (((kk * 4 + lg) ^ (row & 7)) << 4));
      }
#pragma unroll
      for (int n = 0; n < 4; ++n) {
        const int row = wn * 64 + n * 16 + lq;
        bf[n] = *(const f16x8*)((const char*)Bs + row * 128 +
                                (((kk * 4 + lg) ^ (row & 7)) << 4));
      }
#pragma unroll
      for (int m = 0; m < 4; ++m)
#pragma unroll
        for (int n = 0; n < 4; ++n) acc[m][n] = MFMA16(af[m], bf[n], acc[m][n]);
    }
    __syncthreads();
  }

#pragma unroll
  for (int m = 0; m < 4; ++m) {
    const int rbase = r0 + wm * 64 + m * 16 + lg * 4;
#pragma unroll
    for (int n = 0; n < 4; ++n) {
      const int col = c0 + wn * 64 + n * 16 + lq;
      if (NCHK && col >= N) continue;
      const float bsum = bias[col] + (bias2 ? bias2[col] : 0.f);
      const f32x4 a = acc[m][n];
      if (EPI == 3) {  // V: (B,NH,D,T)
        const int b = rbase >> 10, t = rbase & (T_ - 1);
        const int head = col >> 6, d = col & 63;
        f16x4 pk;
#pragma unroll
        for (int r = 0; r < 4; ++r) pk[r] = (f16)((a[r] + bsum) * scale);
        *(f16x4*)((f16*)outp + ((size_t)((b * NH_ + head) * D_ + d)) * T_ + t) =
            pk;
      } else {
#pragma unroll
        for (int r = 0; r < 4; ++r) {
          const int row = rbase + r;
          float v = (a[r] + bsum) * scale;
          if (EPI == 1) v = fmaxf(v, 0.f);
          if (EPI == 4)
            ((float*)outp)[(size_t)row * N + col] = v;
          else
            ((f16*)outp)[(size_t)row * N + col] = (f16)v;
        }
      }
    }
  }
}

// ---------------------------------------------------------------------------
// Fused zero-state LSTM v2: h = sig(o)*tanh(sig(i)*tanh(g)).
// 128x128 block tile, 4 waves (2m x 2n), wave tile 64x64 x 3 gates.
// acc[3][4][4] f32x4 = 192 VGPR; per K-step/wave 32 ds_read : 96 MFMA.
// Inner loop + epilogue index math identical to validated mgemm.
// ---------------------------------------------------------------------------
template <bool CONCATA>
__global__ __launch_bounds__(256, 2) void lstm_fused(
    const f16* __restrict__ A, const f16* __restrict__ A2,
    const f16* __restrict__ Wih, const float* __restrict__ bih,
    const float* __restrict__ bhh, f16* __restrict__ Hout_) {
  constexpr int K = CONCATA ? 1024 : 512;
  __shared__ f16 As[128 * 64];
  __shared__ f16 Bs[3][128 * 64];
  const int tid = threadIdx.x;
  const int lane = tid & 63, wid = tid >> 6;  // 4 waves
  const int lq = lane & 15, lg = lane >> 4;
  const int wm = wid >> 1, wn = wid & 1;  // 2m x 2n
  const int r0 = blockIdx.x * 128, c0 = blockIdx.y * 128;

  f32x4 acc[3][4][4] = {};

  for (int k0 = 0; k0 < K; k0 += 64) {
#pragma unroll
    for (int it = 0; it < 4; ++it) {
      const int off = it * 4096 + tid * 16;
      const int row = off >> 7;
      const int cb = (off >> 4) & 7;
      const int kc = k0 + ((cb ^ (row & 7)) << 3);
      const f16* src;
      if (CONCATA) {
        src = (kc < 512) ? (A + (size_t)(r0 + row) * 512 + kc)
                         : (A2 + (size_t)(r0 + row) * 512 + (kc - 512));
      } else {
        src = A + (size_t)(r0 + row) * K + kc;
      }
      gload_lds16(src, (f16*)((char*)As + off));
    }
#pragma unroll
    for (int g = 0; g < 3; ++g) {
      const int gbase = (g == 0) ? 0 : 512 * (g + 1);  // i=0, g=1024, o=1536
#pragma unroll
      for (int it = 0; it < 4; ++it) {
        const int off = it * 4096 + tid * 16;
        const int row = off >> 7;
        const int cb = (off >> 4) & 7;
        gload_lds16(
            Wih + (size_t)(gbase + c0 + row) * K + k0 + ((cb ^ (row & 7)) << 3),
            (f16*)((char*)&Bs[g][0] + off));
      }
    }
    __syncthreads();
#pragma unroll
    for (int kk = 0; kk < 2; ++kk) {
      f16x8 af[4];
#pragma unroll
      for (int m = 0; m < 4; ++m) {
        const int row = wm * 64 + m * 16 + lq;
        af[m] = *(const f16x8*)((const char*)As + row * 128 +
                                (((kk * 4 + lg) ^ (row & 7)) << 4));
      }
#pragma unroll
      for (int g = 0; g < 3; ++g)
#pragma unroll
        for (int n = 0; n < 4; ++n) {
          const int row = wn * 64 + n * 16 + lq;
          const f16x8 bf = *(const f16x8*)((const char*)&Bs[g][0] + row * 128 +
                                           (((kk * 4 + lg) ^ (row & 7)) << 4));
#pragma unroll
          for (int m = 0; m < 4; ++m)
            acc[g][m][n] = MFMA16(af[m], bf, acc[g][m][n]);
        }
    }
    __syncthreads();
  }

#pragma unroll
  for (int n = 0; n < 4; ++n) {
    const int c = c0 + wn * 64 + n * 16 + lq;
    const float bi = bih[c] + bhh[c];
    const float bg = bih[1024 + c] + bhh[1024 + c];
    const float bo = bih[1536 + c] + bhh[1536 + c];
#pragma unroll
    for (int m = 0; m < 4; ++m) {
      const int rbase = r0 + wm * 64 + m * 16 + lg * 4;
#pragma unroll
      for (int r = 0; r < 4; ++r) {
        const float gi = acc[0][m][n][r] + bi;
        const float gg = acc[1][m][n][r] + bg;
        const float go = acc[2][m][n][r] + bo;
        const float si = 1.f / (1.f + __expf(-gi));
        const float so = 1.f / (1.f + __expf(-go));
        const float tg = 2.f / (1.f + __expf(-2.f * gg)) - 1.f;
        const float cc = si * tg;
        const float tc = 2.f / (1.f + __expf(-2.f * cc)) - 1.f;
        Hout_[(size_t)(rbase + r) * 512 + c] = (f16)(so * tc);
      }
    }
  }
}

// ---------------------------------------------------------------------------
// Fused k+v projection: one enc staging, two weight/gate pipes.
// Wt points at Wk (inw + 512*512); gate g rows at g*512. bias = inb+512,
// gate bias offset g*512. k -> (B,T,H) plain; v -> (B,NH,D,T) transposed.
// ---------------------------------------------------------------------------
__global__ __launch_bounds__(256, 2) void kv_fused(
    const f16* __restrict__ A, const f16* __restrict__ Wt,
    const float* __restrict__ bias, f16* __restrict__ kout,
    f16* __restrict__ vout) {
  constexpr int K = 512;
  __shared__ f16 As[128 * 64];
  __shared__ f16 Bs[2][128 * 64];
  const int tid = threadIdx.x;
  const int lane = tid & 63, wid = tid >> 6;
  const int lq = lane & 15, lg = lane >> 4;
  const int wm = wid >> 1, wn = wid & 1;
  const int r0 = blockIdx.x * 128, c0 = blockIdx.y * 128;

  f32x4 acc[2][4][4] = {};

  for (int k0 = 0; k0 < K; k0 += 64) {
#pragma unroll
    for (int it = 0; it < 4; ++it) {
      const int off = it * 4096 + tid * 16;
      const int row = off >> 7;
      const int cb = (off >> 4) & 7;
      const int kc = k0 + ((cb ^ (row & 7)) << 3);
      gload_lds16(A + (size_t)(r0 + row) * K + kc, (f16*)((char*)As + off));
    }
#pragma unroll
    for (int g = 0; g < 2; ++g) {
#pragma unroll
      for (int it = 0; it < 4; ++it) {
        const int off = it * 4096 + tid * 16;
        const int row = off >> 7;
        const int cb = (off >> 4) & 7;
        gload_lds16(
            Wt + (size_t)(g * 512 + c0 + row) * K + k0 + ((cb ^ (row & 7)) << 3),
            (f16*)((char*)&Bs[g][0] + off));
      }
    }
    __syncthreads();
#pragma unroll
    for (int kk = 0; kk < 2; ++kk) {
      f16x8 af[4];
#pragma unroll
      for (int m = 0; m < 4; ++m) {
        const int row = wm * 64 + m * 16 + lq;
        af[m] = *(const f16x8*)((const char*)As + row * 128 +
                                (((kk * 4 + lg) ^ (row & 7)) << 4));
      }
#pragma unroll
      for (int g = 0; g < 2; ++g)
#pragma unroll
        for (int n = 0; n < 4; ++n) {
          const int row = wn * 64 + n * 16 + lq;
          const f16x8 bf = *(const f16x8*)((const char*)&Bs[g][0] + row * 128 +
                                           (((kk * 4 + lg) ^ (row & 7)) << 4));
#pragma unroll
          for (int m = 0; m < 4; ++m)
            acc[g][m][n] = MFMA16(af[m], bf, acc[g][m][n]);
        }
    }
    __syncthreads();
  }

#pragma unroll
  for (int m = 0; m < 4; ++m) {
    const int rbase = r0 + wm * 64 + m * 16 + lg * 4;
    const int b = rbase >> 10, t = rbase & (T_ - 1);
#pragma unroll
    for (int n = 0; n < 4; ++n) {
      const int col = c0 + wn * 64 + n * 16 + lq;
      // k: plain (B,T,H)
      const float bk = bias[col];
#pragma unroll
      for (int r = 0; r < 4; ++r)
        kout[(size_t)(rbase + r) * 512 + col] = (f16)(acc[0][m][n][r] + bk);
      // v: transposed (B,NH,D,T)
      const float bv = bias[512 + col];
      const int head = col >> 6, d = col & 63;
      f16x4 pk;
#pragma unroll
      for (int r = 0; r < 4; ++r) pk[r] = (f16)(acc[1][m][n][r] + bv);
      *(f16x4*)(vout + ((size_t)((b * NH_ + head) * D_ + d)) * T_ + t) = pk;
    }
  }
}

// ---------------------------------------------------------------------------
// Flash attention v3 [validated R5, unchanged].
// ---------------------------------------------------------------------------
__global__ __launch_bounds__(256) void attn_mfma3(
    const f16* __restrict__ q, const f16* __restrict__ k,
    const f16* __restrict__ vT, f16* __restrict__ ctx) {
  __shared__ f16 Ks[2][64 * 64];
  __shared__ f16 Vs[2][64 * 64];
  __shared__ f16 Ps[4][16 * 64];
  const int qt = blockIdx.x, head = blockIdx.y, b = blockIdx.z;
  const int tid = threadIdx.x, lane = tid & 63, wid = tid >> 6;
  const int lq = lane & 15, lg = lane >> 4;
  const int bh = b * NH_ + head;

  const f16* kbase = k + ((size_t)b * T_) * H_ + head * D_;
  const f16* vbase = vT + (size_t)bh * D_ * T_;

  auto stage = [&](int kt, int buf) {
#pragma unroll
    for (int it = 0; it < 2; ++it) {
      const int off = it * 4096 + tid * 16;
      const int row = off >> 7;
      const int sc = ((((off >> 4) & 7) ^ (row & 7)) << 3);
      gload_lds16(kbase + (size_t)(kt * 64 + row) * H_ + sc,
                  (f16*)((char*)&Ks[buf][0] + off));
      gload_lds16(vbase + (size_t)row * T_ + kt * 64 + sc,
                  (f16*)((char*)&Vs[buf][0] + off));
    }
  };

  const int q0 = qt * 128 + wid * 32;
  f16x8 qf[2][2];
#pragma unroll
  for (int s = 0; s < 2; ++s)
#pragma unroll
    for (int kk = 0; kk < 2; ++kk)
      qf[s][kk] = *(const f16x8*)(q + ((size_t)(b * T_) + q0 + s * 16 + lq) * H_ +
                                  head * D_ + kk * 32 + lg * 8);

  float m_run[2] = {-1e30f, -1e30f}, l_run[2] = {0.f, 0.f};
  f32x4 accO[2][4] = {};
  char* pw = (char*)&Ps[wid][0] + lq * 128;
  const int psw = (lq & 3) << 5;

  stage(0, 0);
  __syncthreads();

  for (int kt = 0; kt < T_ / 64; ++kt) {
    const int cur = kt & 1;
    if (kt < T_ / 64 - 1) stage(kt + 1, cur ^ 1);

    f16x8 kf[4][2];
#pragma unroll
    for (int n = 0; n < 4; ++n)
#pragma unroll
      for (int kk = 0; kk < 2; ++kk) {
        const int row = n * 16 + lq;
        kf[n][kk] = *(const f16x8*)((const char*)&Ks[cur][0] + row * 128 +
                                    (((kk * 4 + lg) ^ (row & 7)) << 4));
      }
    f32x4 ssw[2][4] = {};
    __builtin_amdgcn_s_setprio(1);
#pragma unroll
    for (int s = 0; s < 2; ++s)
#pragma unroll
      for (int n = 0; n < 4; ++n)
#pragma unroll
        for (int kk = 0; kk < 2; ++kk)
          ssw[s][n] = MFMA16(kf[n][kk], qf[s][kk], ssw[s][n]);
    __builtin_amdgcn_s_setprio(0);

    f16x8 vf[4][2];
#pragma unroll
    for (int n = 0; n < 4; ++n)
#pragma unroll
      for (int kk = 0; kk < 2; ++kk) {
        const int row = n * 16 + lq;
        vf[n][kk] = *(const f16x8*)((const char*)&Vs[cur][0] + row * 128 +
                                    (((kk * 4 + lg) ^ (row & 7)) << 4));
      }

#pragma unroll
    for (int s = 0; s < 2; ++s) {
      float mloc = -1e30f;
#pragma unroll
      for (int n = 0; n < 4; ++n)
#pragma unroll
        for (int r = 0; r < 4; ++r) mloc = fmaxf(mloc, ssw[s][n][r]);
      mloc = fmaxf(mloc, __shfl_xor(mloc, 16, 64));
      mloc = fmaxf(mloc, __shfl_xor(mloc, 32, 64));

      const bool noresc = __all(mloc - m_run[s] <= 8.f);
      if (!noresc) {
        const float nm = fmaxf(m_run[s], mloc);
        const float corr = __expf(m_run[s] - nm);
        m_run[s] = nm;
        l_run[s] *= corr;
#pragma unroll
        for (int n = 0; n < 4; ++n) {
          accO[s][n][0] *= corr; accO[s][n][1] *= corr;
          accO[s][n][2] *= corr; accO[s][n][3] *= corr;
        }
      }
      float sl = 0.f;
#pragma unroll
      for (int n = 0; n < 4; ++n) {
        f16x4 pk;
#pragma unroll
        for (int r = 0; r < 4; ++r) {
          const float p = __expf(ssw[s][n][r] - m_run[s]);
          sl += p;
          pk[r] = (f16)p;
        }
        *(f16x4*)(pw + ((n * 32 + lg * 8) ^ psw)) = pk;
      }
      sl += __shfl_xor(sl, 16, 64);
      sl += __shfl_xor(sl, 32, 64);
      l_run[s] += sl;

      f16x8 pb[2];
#pragma unroll
      for (int kk = 0; kk < 2; ++kk)
        pb[kk] = *(const f16x8*)(pw + ((((kk * 4 + lg) << 4)) ^ psw));
      __builtin_amdgcn_s_setprio(1);
#pragma unroll
      for (int n = 0; n < 4; ++n)
#pragma unroll
        for (int kk = 0; kk < 2; ++kk)
          accO[s][n] = MFMA16(vf[n][kk], pb[kk], accO[s][n]);
      __builtin_amdgcn_s_setprio(0);
    }
    __syncthreads();
  }

#pragma unroll
  for (int s = 0; s < 2; ++s) {
    const float inv = 1.f / l_run[s];
    const size_t rowoff = ((size_t)(b * T_) + q0 + s * 16 + lq) * H_ + head * D_;
#pragma unroll
    for (int n = 0; n < 4; ++n) {
      f16x4 o;
#pragma unroll
      for (int r = 0; r < 4; ++r) o[r] = (f16)(accO[s][n][r] * inv);
      *(f16x4*)(ctx + rowoff + n * 16 + lg * 4) = o;
    }
  }
}

// ---------------------------------------------------------------------------
// Merged conversions + small builders [unchanged]
// ---------------------------------------------------------------------------
constexpr int C0 = 2097152;            // enc
constexpr int C1 = C0 + 196608;        // inw
constexpr int C2 = C1 + 65536;         // outw
constexpr int C3 = C2 + 524288;        // wih0
constexpr int C4 = C3 + 262144;        // wih1
constexpr int C5 = C4 + 10240;         // wmel
__global__ void conv_all(const float* __restrict__ enc, const float* __restrict__ inw,
                         const float* __restrict__ outw, const float* __restrict__ wih0,
                         const float* __restrict__ wih1, const float* __restrict__ wmel,
                         f16* denc, f16* dinw, f16* doutw, f16* dwih0,
                         f16* dwih1, f16* dwmel) {
  const int i = blockIdx.x * blockDim.x + threadIdx.x;
  const float* s;
  f16* d;
  int off;
  if (i < C0) { s = enc; d = denc; off = i; }
  else if (i < C1) { s = inw; d = dinw; off = i - C0; }
  else if (i < C2) { s = outw; d = doutw; off = i - C1; }
  else if (i < C3) { s = wih0; d = dwih0; off = i - C2; }
  else if (i < C4) { s = wih1; d = dwih1; off = i - C3; }
  else if (i < C5) { s = wmel; d = dwmel; off = i - C4; }
  else return;
  const float4 v = ((const float4*)s)[off];
  f16x4 o = {(f16)v.x, (f16)v.y, (f16)v.z, (f16)v.w};
  ((f16x4*)d)[off] = o;
}

__global__ void build_pm(const float* __restrict__ tmel, f16* __restrict__ pm) {
  const int i = blockIdx.x * blockDim.x + threadIdx.x;
  const int r = i >> 5, c4 = (i & 31) * 4;
  const int t = r & (T_ - 1);
  f16x4 o = {};
  if (t != 0 && c4 < M_) {
    const float4 v = *(const float4*)(tmel + (size_t)(r - 1) * M_ + c4);
    o = {(f16)v.x, (f16)v.y, (f16)v.z, (f16)v.w};
  }
  *(f16x4*)(pm + (size_t)r * 128 + c4) = o;
}

__global__ void build_wp(const float* __restrict__ w, f16* __restrict__ wp) {
  const int i = blockIdx.x * blockDim.x + threadIdx.x;
  const int r = i >> 5, c4 = (i & 31) * 4;
  f16x4 o = {};
  if (c4 < M_) {
    const float4 v = *(const float4*)(w + (size_t)r * M_ + c4);
    o = {(f16)v.x, (f16)v.y, (f16)v.z, (f16)v.w};
  }
  *(f16x4*)(wp + (size_t)r * 128 + c4) = o;
}

// ---------------------------------------------------------------------------
extern "C" void kernel_launch(void* const* d_in, const int* in_sizes, int n_in,
                              void* d_out, int out_size, void* d_ws,
                              size_t ws_size, hipStream_t stream) {
  const float* enc = (const float*)d_in[0];
  const float* tmel = (const float*)d_in[1];
  const float* w_pre = (const float*)d_in[2];
  const float* b_pre = (const float*)d_in[3];
  const float* inw = (const float*)d_in[4];
  const float* inb = (const float*)d_in[5];
  const float* outw = (const float*)d_in[6];
  const float* outb = (const float*)d_in[7];
  const float* wih0 = (const float*)d_in[8];
  const float* bih0 = (const float*)d_in[10];
  const float* bhh0 = (const float*)d_in[11];
  const float* wih1 = (const float*)d_in[12];
  const float* bih1 = (const float*)d_in[14];
  const float* bhh1 = (const float*)d_in[15];
  const float* wmel = (const float*)d_in[16];
  const float* bmel = (const float*)d_in[17];

  f16* wsh = (f16*)d_ws;
  const size_t SEG = (size_t)N_ * H_;
  f16* EncB = wsh;                     // S0; reused as aout
  f16* h1 = wsh + SEG;                 // S1
  f16* pre = wsh + 2 * SEG;            // S2
  f16* qb = wsh + 3 * SEG;             // S3; reused as h2
  f16* kbuf = wsh + 4 * SEG;           // S4
  f16* vTb = wsh + 5 * SEG;            // S5
  f16* ctx = wsh + 6 * SEG;            // S6
  f16* aout = EncB;
  f16* h2 = qb;
  f16* WP = wsh + 7 * SEG;
  f16* WIN = WP + 512 * 128;
  f16* WOUT = WIN + 1536 * 512;
  f16* WIH0 = WOUT + 512 * 512;
  f16* WIH1 = WIH0 + 2048 * 1024;
  f16* WMEL = WIH1 + 2048 * 512;
  f16* PM = WMEL + 80 * 512;

  const dim3 blk(256);
  conv_all<<<(C5 + 255) / 256, blk, 0, stream>>>(enc, inw, outw, wih0, wih1,
                                                 wmel, EncB, WIN, WOUT, WIH0,
                                                 WIH1, WMEL);
  build_pm<<<(N_ * 32) / 256, blk, 0, stream>>>(tmel, PM);
  build_wp<<<(512 * 32) / 256, blk, 0, stream>>>(w_pre, WP);

  const dim3 g512(N_ / 128, 4), g80(N_ / 128, 1);
  mgemm<1, false, false><<<g512, blk, 0, stream>>>(PM, nullptr, WP, b_pre,
                                                   nullptr, 1.f, pre, 128, 512);
  mgemm<0, false, false><<<g512, blk, 0, stream>>>(pre, nullptr, WIN, inb,
                                                   nullptr, 0.125f, qb, 512, 512);
  kv_fused<<<g512, blk, 0, stream>>>(EncB, WIN + 512 * 512, inb + 512, kbuf,
                                     vTb);
  attn_mfma3<<<dim3(T_ / 128, NH_, B_), blk, 0, stream>>>(qb, kbuf, vTb, ctx);
  mgemm<0, false, false><<<g512, blk, 0, stream>>>(ctx, nullptr, WOUT, outb,
                                                   nullptr, 1.f, aout, 512, 512);
  lstm_fused<true><<<g512, blk, 0, stream>>>(pre, aout, WIH0, bih0, bhh0, h1);
  lstm_fused<false><<<g512, blk, 0, stream>>>(h1, nullptr, WIH1, bih1, bhh1, h2);
  mgemm<4, false, true><<<g80, blk, 0, stream>>>(h2, nullptr, WMEL, bmel,
                                                 nullptr, 1.f, (float*)d_out,
                                                 512, 80);
}